// Round 2
// baseline (393.318 us; speedup 1.0000x reference)
//
#include <hip/hip_runtime.h>

// ---- problem constants ----
#define B_   2
#define L_   4096
#define DM   768
#define DI   1536     // D_INNER
#define DS   64       // D_STATE
#define H_   24       // NHEADS
#define P_   64       // HEADDIM
#define CD   1664     // CONV_DIM
#define NPJ  3224     // D_IN_PROJ
#define N1   3200     // GEMM1 useful cols (z + xBC; dt cols done exactly in k_dt2)
#define Q_   64       // chunk length
#define NC   64       // chunks per batch
#define SP   76       // LDS row stride (floats) for k_inter tiles
#define HS   72       // fp16 LDS row stride (halves): <=2-way conflicts
#define WDS  772      // k_dt2 LDS W stride
#define CROWS 16      // conv rows per thread

typedef short          bf16x8 __attribute__((ext_vector_type(8)));
typedef _Float16       f16x8  __attribute__((ext_vector_type(8)));
typedef unsigned short us8    __attribute__((ext_vector_type(8)));
typedef unsigned short us4    __attribute__((ext_vector_type(4)));
typedef float          f32x4  __attribute__((ext_vector_type(4)));

__device__ __forceinline__ unsigned short f2bf(float f) {
  unsigned u = __float_as_uint(f);
  u += 0x7fffu + ((u >> 16) & 1u);   // RNE
  return (unsigned short)(u >> 16);
}
__device__ __forceinline__ float bf2f(unsigned short u) {
  return __uint_as_float(((unsigned)u) << 16);
}
__device__ __forceinline__ float siluf(float x) { return x / (1.f + expf(-x)); }
__device__ __forceinline__ float softplusf(float x) { return (x > 20.f) ? x : log1pf(expf(x)); }

// async global->LDS, 16B per lane; LDS dest = uniform base + lane*16
__device__ __forceinline__ void gload16(const unsigned short* g, unsigned short* l) {
  __builtin_amdgcn_global_load_lds(
      (const __attribute__((address_space(1))) void*)g,
      (__attribute__((address_space(3))) void*)l, 16, 0, 0);
}

// ---------------- transpose + cast (R x C fp32) -> (C x R bf16) ----------------
__global__ __launch_bounds__(256)
void k_transpose_cast(const float* __restrict__ src, unsigned short* __restrict__ dst,
                      int R, int C)
{
  __shared__ float tile[32][33];
  const int tx = threadIdx.x & 31, ty = threadIdx.x >> 5;
  const int r0 = blockIdx.x * 32, c0 = blockIdx.y * 32;
#pragma unroll
  for (int r = 0; r < 4; ++r) {
    int rr = r0 + ty + r * 8, cc = c0 + tx;
    if (rr < R && cc < C) tile[ty + r * 8][tx] = src[(size_t)rr * C + cc];
  }
  __syncthreads();
#pragma unroll
  for (int r = 0; r < 4; ++r) {
    int orow = c0 + ty + r * 8, ocol = r0 + tx;
    if (orow < C && ocol < R) dst[(size_t)orow * R + ocol] = f2bf(tile[tx][ty + r * 8]);
  }
}

// ---------------- gather dt columns of W_in -> contiguous fp32 WdtT[24][768] ----------------
__global__ void k_wdtT(const float* __restrict__ W_in, float* __restrict__ WdtT)
{
  const int idx = blockIdx.x * 256 + threadIdx.x;
  if (idx >= H_ * DM) return;
  const int k = idx / H_, h = idx % H_;
  WdtT[(size_t)h * DM + k] = W_in[(size_t)k * NPJ + N1 + h];
}

// ---------------- bf16 MFMA GEMM, BK=64, XOR-swizzled LDS (conflict-free) ----------------
// LDS-read-BW is the limiter (r1 evidence): MfmaUtil scales with 1/(ds_reads per MFMA).
// Wave tile 64x64 -> 0.5 reads/MFMA; 128x64 -> 0.375. In-proj uses <256,128,128,64>.
template<int BM, int BN, int WM, int WN, bool OUT_BF16>
__global__ __launch_bounds__(256)
void k_gemm_t(const unsigned short* __restrict__ A, const unsigned short* __restrict__ Bt,
              void* __restrict__ C0v, int ld0, int ncol0,
              void* __restrict__ C1v, int ld1, int K)
{
  constexpr int MI = WM / 16, NI = WN / 16;
  constexpr int WAVES_N = BN / WN;
  constexpr int RA = BM / 32, RB = BN / 32;
  const int m0 = blockIdx.x * BM, n0 = blockIdx.y * BN;
  __shared__ unsigned short As[BM][64];
  __shared__ unsigned short Bs[BN][64];
  const int tid  = threadIdx.x;
  const int wave = tid >> 6, lane = tid & 63;
  const int quad = lane >> 4, r16 = lane & 15;
  const int wm = (wave / WAVES_N) * WM, wn = (wave % WAVES_N) * WN;

  const int lr8 = lane >> 3;                                // 0..7 row-in-band
  const int csw = ((lane & 7) ^ lr8) * 8;                   // swizzled source col (shorts)
  const unsigned short* gA = A  + (size_t)(m0 + wave * 8 + lr8) * K + csw;
  const unsigned short* gB = Bt + (size_t)(n0 + wave * 8 + lr8) * K + csw;
  unsigned short* lA = &As[wave * 8][0] + (size_t)lane * 8; // +lane*16B
  unsigned short* lB = &Bs[wave * 8][0] + (size_t)lane * 8;

  f32x4 acc[MI][NI];
#pragma unroll
  for (int mi = 0; mi < MI; ++mi)
#pragma unroll
    for (int ni = 0; ni < NI; ++ni) acc[mi][ni] = (f32x4){0.f, 0.f, 0.f, 0.f};

  for (int k0 = 0; k0 < K; k0 += 64) {
#pragma unroll
    for (int r = 0; r < RA; ++r)
      gload16(gA + (size_t)(r * 32) * K + k0, lA + (size_t)r * 32 * 64);
#pragma unroll
    for (int r = 0; r < RB; ++r)
      gload16(gB + (size_t)(r * 32) * K + k0, lB + (size_t)r * 32 * 64);
    __syncthreads();
    bf16x8 af[MI][2], bfr[NI][2];
#pragma unroll
    for (int mi = 0; mi < MI; ++mi)
#pragma unroll
      for (int ks = 0; ks < 2; ++ks)
        af[mi][ks] = *(const bf16x8*)&As[wm + mi * 16 + r16][((quad + ks * 4) ^ (r16 & 7)) * 8];
#pragma unroll
    for (int ni = 0; ni < NI; ++ni)
#pragma unroll
      for (int ks = 0; ks < 2; ++ks)
        bfr[ni][ks] = *(const bf16x8*)&Bs[wn + ni * 16 + r16][((quad + ks * 4) ^ (r16 & 7)) * 8];
#pragma unroll
    for (int mi = 0; mi < MI; ++mi)
#pragma unroll
      for (int ni = 0; ni < NI; ++ni)
#pragma unroll
        for (int ks = 0; ks < 2; ++ks)
          acc[mi][ni] = __builtin_amdgcn_mfma_f32_16x16x32_bf16(
              af[mi][ks], bfr[ni][ks], acc[mi][ni], 0, 0, 0);
    __syncthreads();
  }
#pragma unroll
  for (int mi = 0; mi < MI; ++mi)
#pragma unroll
    for (int ni = 0; ni < NI; ++ni) {
      int col = n0 + wn + ni * 16 + r16;
      void* dst; int ld, c;
      if (col < ncol0) { dst = C0v; ld = ld0; c = col; }
      else             { dst = C1v; ld = ld1; c = col - ncol0; }
#pragma unroll
      for (int r = 0; r < 4; ++r) {
        int row = m0 + wm + mi * 16 + quad * 4 + r;
        if (OUT_BF16) ((unsigned short*)dst)[(size_t)row * ld + c] = f2bf(acc[mi][ni][r]);
        else          ((float*)dst)[(size_t)row * ld + c] = acc[mi][ni][r];
      }
    }
}

// ---------------- depthwise conv(4) + silu: sliding window, batch-boundary aware ----------------
__global__ __launch_bounds__(256)
void k_conv2(const unsigned short* __restrict__ xbc, const float* __restrict__ cw,
             const float* __restrict__ cb, _Float16* __restrict__ xs,
             float* __restrict__ Bm, float* __restrict__ Cm)
{
  const int ch = blockIdx.x * 256 + threadIdx.x;
  if (ch >= CD) return;
  const int r0 = blockIdx.y * CROWS;
  const float w0 = cw[ch * 4], w1 = cw[ch * 4 + 1], w2 = cw[ch * 4 + 2], w3 = cw[ch * 4 + 3];
  const float bias = cb[ch];
  float a, b, c;
  if ((r0 & (L_ - 1)) == 0) {                 // batch start: zero history
    a = 0.f; b = 0.f; c = 0.f;
  } else {
    a = bf2f(xbc[(size_t)(r0 - 3) * CD + ch]);
    b = bf2f(xbc[(size_t)(r0 - 2) * CD + ch]);
    c = bf2f(xbc[(size_t)(r0 - 1) * CD + ch]);
  }
#pragma unroll
  for (int i = 0; i < CROWS; ++i) {
    const int lr = r0 + i;
    float d = bf2f(xbc[(size_t)lr * CD + ch]);
    float v = siluf(bias + a * w0 + b * w1 + c * w2 + d * w3);
    a = b; b = c; c = d;
    if (ch < DI)           xs[(size_t)lr * DI + ch] = (_Float16)v;
    else if (ch < DI + DS) Bm[(size_t)lr * DS + (ch - DI)] = v;
    else                   Cm[(size_t)lr * DS + (ch - DI - DS)] = v;
  }
}

// ---------------- exact fp32 dt via LDS-staged WdtT + fused x->bf16 cast ----------------
// block = 192 threads = 24 heads x 8 rows; thread h also casts x chunk [h*32,h*32+32)
__global__ __launch_bounds__(192)
void k_dt2(const float* __restrict__ x, const float* __restrict__ WdtT,
           const float* __restrict__ dt_bias, float* __restrict__ dtv,
           unsigned short* __restrict__ xb)
{
  __shared__ float sW[H_][WDS];
  for (int i = threadIdx.x; i < H_ * DM; i += 192)
    sW[i / DM][i % DM] = WdtT[i];
  const int h = threadIdx.x % H_, rloc = threadIdx.x / H_;
  const int lrow = blockIdx.x * 8 + rloc;
  const float* xr = x + (size_t)lrow * DM;
  __syncthreads();
  float acc = 0.f;
#pragma unroll 8
  for (int k = 0; k < DM; k += 4) {
    f32x4 xv = *(const f32x4*)(xr + k);
    f32x4 wv = *(const f32x4*)&sW[h][k];
    acc += xv[0] * wv[0] + xv[1] * wv[1] + xv[2] * wv[2] + xv[3] * wv[3];
  }
  dtv[(size_t)lrow * H_ + h] = softplusf(acc + dt_bias[h]);
  // fused cast: 32-elem chunk per thread (L1-hot re-read)
  const float* xi = xr + h * 32;
  unsigned short* xo = xb + (size_t)lrow * DM + h * 32;
#pragma unroll
  for (int j = 0; j < 32; j += 8) {
    f32x4 a = *(const f32x4*)(xi + j);
    f32x4 b = *(const f32x4*)(xi + j + 4);
    us8 o;
#pragma unroll
    for (int e = 0; e < 4; ++e) { o[e] = f2bf(a[e]); o[e + 4] = f2bf(b[e]); }
    *(us8*)(xo + j) = o;
  }
}

// ---------------- per-chunk inclusive cumsum of dt*A ----------------
__global__ void k_cum(const float* __restrict__ dtv, const float* __restrict__ A_log,
                      float* __restrict__ cumA, int n)
{
  const int idx = blockIdx.x * 256 + threadIdx.x;      // ((bz*H+h)*NC + c)
  if (idx >= n) return;
  const int c = idx % NC;
  const int h = (idx / NC) % H_;
  const int bz = idx / (NC * H_);
  const float A = -expf(A_log[h]);
  float cum = 0.f;
  const int rowbase = bz * L_ + c * Q_;
  float* outp = cumA + (size_t)idx * Q_;
  for (int i = 0; i < Q_; ++i) {
    cum += dtv[(size_t)(rowbase + i) * H_ + h] * A;
    outp[i] = cum;
  }
}

// ---------------- intra-chunk via fp16 MFMA; ytot/Sbuf stored fp16 ----------------
__global__ __launch_bounds__(256)
void k_intra(const _Float16* __restrict__ xs, const float* __restrict__ Bm,
             const float* __restrict__ Cm, const float* __restrict__ dtv,
             const float* __restrict__ cumA, _Float16* __restrict__ ytot,
             _Float16* __restrict__ Sbuf)
{
  const int c = blockIdx.x, h = blockIdx.y, bz = blockIdx.z;
  const int gidx = (bz * H_ + h) * NC + c;
  __shared__ _Float16 sCW[Q_][HS];   // C, then W
  __shared__ _Float16 sB [Q_][HS];
  __shared__ _Float16 sBT[Q_][HS];   // (coef_j * B[j][n]) transposed -> [n][j]
  __shared__ _Float16 sXT[Q_][HS];   // X transposed -> [p][j]
  __shared__ float scum[Q_], sdt[Q_];
  const int tid = threadIdx.x;
  const int rowbase = bz * L_ + c * Q_;

  {
    const int j = tid >> 2, s16 = (tid & 3) * 16;
    if (tid < Q_) {
      scum[tid] = cumA[(size_t)gidx * Q_ + tid];
      sdt[tid]  = dtv[(size_t)(rowbase + tid) * H_ + h];
    }
    const _Float16* xsrc = xs + (size_t)(rowbase + j) * DI + h * P_ + s16;
    f16x8 xv0 = *(const f16x8*)xsrc;
    f16x8 xv1 = *(const f16x8*)(xsrc + 8);
    f32x4 bv[4], cv[4];
    const float* bsrc = Bm + (size_t)(rowbase + j) * DS + s16;
    const float* csrc = Cm + (size_t)(rowbase + j) * DS + s16;
#pragma unroll
    for (int q = 0; q < 4; ++q) {
      bv[q] = *(const f32x4*)(bsrc + q * 4);
      cv[q] = *(const f32x4*)(csrc + q * 4);
    }
    __syncthreads();
    const float coef = expf(scum[Q_ - 1] - scum[j]) * sdt[j];
    union { f16x8 v; _Float16 e[8]; } pc[2], pb[2];
#pragma unroll
    for (int q = 0; q < 4; ++q)
#pragma unroll
      for (int e = 0; e < 4; ++e) {
        int o = q * 4 + e;
        pc[o >> 3].e[o & 7] = (_Float16)cv[q][e];
        pb[o >> 3].e[o & 7] = (_Float16)bv[q][e];
        sBT[s16 + o][j] = (_Float16)(bv[q][e] * coef);
        sXT[s16 + o][j] = (o < 8) ? xv0[o] : xv1[o - 8];
      }
    *(f16x8*)&sCW[j][s16]     = pc[0].v;
    *(f16x8*)&sCW[j][s16 + 8] = pc[1].v;
    *(f16x8*)&sB [j][s16]     = pb[0].v;
    *(f16x8*)&sB [j][s16 + 8] = pb[1].v;
  }
  __syncthreads();

  const int wave = tid >> 6, lane = tid & 63;
  const int quad = lane >> 4, r16 = lane & 15;
  const int i0 = wave * 16;
  const int irow = i0 + quad * 4;

  f32x4 g[4];
#pragma unroll
  for (int q = 0; q < 4; ++q) g[q] = (f32x4){0.f, 0.f, 0.f, 0.f};
#pragma unroll
  for (int ni = 0; ni < 4; ++ni) {
    if (ni <= wave) {
#pragma unroll
      for (int ks = 0; ks < 2; ++ks)
        g[ni] = __builtin_amdgcn_mfma_f32_16x16x32_f16(
            *(const f16x8*)&sCW[i0 + r16][ks * 32 + quad * 8],
            *(const f16x8*)&sB [ni * 16 + r16][ks * 32 + quad * 8], g[ni], 0, 0, 0);
    }
  }
  float wv[4][4];
#pragma unroll
  for (int ni = 0; ni < 4; ++ni)
#pragma unroll
    for (int r = 0; r < 4; ++r) {
      int i = irow + r, jcol = ni * 16 + r16;
      float v = 0.f;
      if (ni <= wave && jcol <= i)
        v = g[ni][r] * expf(scum[i] - scum[jcol]) * sdt[jcol];
      wv[ni][r] = v;
    }
  __syncthreads();
#pragma unroll
  for (int ni = 0; ni < 4; ++ni)
#pragma unroll
    for (int r = 0; r < 4; ++r)
      sCW[irow + r][ni * 16 + r16] = (_Float16)wv[ni][r];
  __syncthreads();

  f32x4 y[4];
#pragma unroll
  for (int q = 0; q < 4; ++q) y[q] = (f32x4){0.f, 0.f, 0.f, 0.f};
#pragma unroll
  for (int ni = 0; ni < 4; ++ni)
#pragma unroll
    for (int ks = 0; ks < 2; ++ks) {
      if (ks == 0 || wave >= 2)
        y[ni] = __builtin_amdgcn_mfma_f32_16x16x32_f16(
            *(const f16x8*)&sCW[i0 + r16][ks * 32 + quad * 8],
            *(const f16x8*)&sXT[ni * 16 + r16][ks * 32 + quad * 8], y[ni], 0, 0, 0);
    }
#pragma unroll
  for (int ni = 0; ni < 4; ++ni)
#pragma unroll
    for (int r = 0; r < 4; ++r)
      ytot[(size_t)(rowbase + irow + r) * DI + h * P_ + ni * 16 + r16] = (_Float16)y[ni][r];

  f32x4 t4[4];
#pragma unroll
  for (int q = 0; q < 4; ++q) t4[q] = (f32x4){0.f, 0.f, 0.f, 0.f};
#pragma unroll
  for (int ni = 0; ni < 4; ++ni)
#pragma unroll
    for (int ks = 0; ks < 2; ++ks)
      t4[ni] = __builtin_amdgcn_mfma_f32_16x16x32_f16(
          *(const f16x8*)&sBT[i0 + r16][ks * 32 + quad * 8],
          *(const f16x8*)&sXT[ni * 16 + r16][ks * 32 + quad * 8], t4[ni], 0, 0, 0);
  _Float16* sp = Sbuf + (size_t)gidx * (DS * P_);
#pragma unroll
  for (int ni = 0; ni < 4; ++ni)
#pragma unroll
    for (int r = 0; r < 4; ++r)
      sp[(irow + r) * P_ + ni * 16 + r16] = (_Float16)t4[ni][r];
}

// ---------------- sequential inter-chunk recurrence (in-place, fp16 storage) ----------------
__global__ void k_chunkscan(_Float16* __restrict__ Sbuf, const float* __restrict__ cumA)
{
  const int seg = blockIdx.x, h = blockIdx.y, bz = blockIdx.z;
  const int bh = bz * H_ + h;
  __shared__ float dec[NC];
  const int tid = threadIdx.x;
  if (tid < NC) dec[tid] = expf(cumA[((size_t)(bh * NC + tid)) * Q_ + (Q_ - 1)]);
  __syncthreads();
  const size_t off = (size_t)seg * 512 + (size_t)tid * 8;
  float s[8];
#pragma unroll
  for (int e = 0; e < 8; ++e) s[e] = 0.f;
  size_t base = (size_t)bh * NC * (DS * P_) + off;
  for (int c = 0; c < NC; ++c) {
    _Float16* p = Sbuf + base + (size_t)c * (DS * P_);
    f16x8 v = *(const f16x8*)p;
    f16x8 sto;
#pragma unroll
    for (int e = 0; e < 8; ++e) sto[e] = (_Float16)s[e];
    *(f16x8*)p = sto;                    // store state BEFORE chunk c
    const float d = dec[c];
#pragma unroll
    for (int e = 0; e < 8; ++e) s[e] = s[e] * d + (float)v[e];
  }
}

// ---------------- inter-chunk correction + D*x (ytot fp16 RMW) ----------------
__global__ __launch_bounds__(256)
void k_inter(const _Float16* __restrict__ xs, const float* __restrict__ Cm,
             const float* __restrict__ cumA, const _Float16* __restrict__ Sbuf,
             const float* __restrict__ Dp, _Float16* __restrict__ ytot)
{
  const int c = blockIdx.x, h = blockIdx.y, bz = blockIdx.z;
  const int gidx = (bz * H_ + h) * NC + c;
  __shared__ float sS[DS][SP];
  __shared__ float sC[Q_][SP];
  __shared__ float scum[Q_];
  const int tid = threadIdx.x;
  const int jr = tid >> 2, blk = (tid & 3) * 16;
  const int rowbase = bz * L_ + c * Q_;
  {
    const _Float16* ssrc = Sbuf + (size_t)gidx * (DS * P_) + jr * P_ + blk;
    f16x8 sv0 = *(const f16x8*)ssrc;
    f16x8 sv1 = *(const f16x8*)(ssrc + 8);
    const float* csrc = Cm + (size_t)(rowbase + jr) * DS + blk;
#pragma unroll
    for (int o = 0; o < 8; ++o) {
      sS[jr][blk + o]     = (float)sv0[o];
      sS[jr][blk + 8 + o] = (float)sv1[o];
    }
#pragma unroll
    for (int q = 0; q < 4; ++q)
      *(f32x4*)&sC[jr][blk + q * 4] = *(const f32x4*)(csrc + q * 4);
    if (tid < Q_) scum[tid] = cumA[(size_t)gidx * Q_ + tid];
  }
  __syncthreads();
  const int i = jr;
  f32x4 acc[4];
#pragma unroll
  for (int q = 0; q < 4; ++q) acc[q] = (f32x4){0.f, 0.f, 0.f, 0.f};
  for (int n = 0; n < DS; ++n) {
    float cv = sC[i][n];
#pragma unroll
    for (int q = 0; q < 4; ++q) acc[q] += cv * *(const f32x4*)&sS[n][blk + q * 4];
  }
  const float e = expf(scum[i]);
  const float Dh = Dp[h];
  _Float16* yt = ytot + (size_t)(rowbase + i) * DI + h * P_ + blk;
  const _Float16* xsr = xs + (size_t)(rowbase + i) * DI + h * P_ + blk;
  f16x8 xa = *(const f16x8*)xsr;
  f16x8 xb2 = *(const f16x8*)(xsr + 8);
  f16x8 y0 = *(const f16x8*)yt;
  f16x8 y1 = *(const f16x8*)(yt + 8);
#pragma unroll
  for (int o = 0; o < 16; ++o) {
    float cur = (float)((o < 8) ? y0[o] : y1[o - 8]);
    float xf  = (float)((o < 8) ? xa[o] : xb2[o - 8]);
    cur += e * acc[o >> 2][o & 3] + Dh * xf;
    if (o < 8) y0[o] = (_Float16)cur; else y1[o - 8] = (_Float16)cur;
  }
  *(f16x8*)yt = y0;
  *(f16x8*)(yt + 8) = y1;
}

// ---------------- gate (silu(z)) + RMSNorm + cast bf16 ----------------
__global__ __launch_bounds__(192)
void k_rms(const unsigned short* __restrict__ z, const _Float16* __restrict__ ytot,
           const float* __restrict__ norm_w, unsigned short* __restrict__ ynorm)
{
  const int row = blockIdx.x, tid = threadIdx.x;
  const int e0 = tid * 8;
  us8 zv = *(const us8*)(z + (size_t)row * DI + e0);
  f16x8 yv = *(const f16x8*)(ytot + (size_t)row * DI + e0);
  float g[8];
  float ss = 0.f;
#pragma unroll
  for (int q = 0; q < 8; ++q) {
    g[q] = (float)yv[q] * siluf(bf2f(zv[q]));
    ss += g[q] * g[q];
  }
#pragma unroll
  for (int off = 32; off > 0; off >>= 1) ss += __shfl_down(ss, off);
  __shared__ float wsum[3];
  __shared__ float sscale;
  if ((tid & 63) == 0) wsum[tid >> 6] = ss;
  __syncthreads();
  if (tid == 0) sscale = rsqrtf((wsum[0] + wsum[1] + wsum[2]) * (1.f / DI) + 1e-5f);
  __syncthreads();
  const float sc = sscale;
  us8 o;
#pragma unroll
  for (int q = 0; q < 8; ++q) o[q] = f2bf(g[q] * sc * norm_w[e0 + q]);
  *(us8*)(ynorm + (size_t)row * DI + e0) = o;
}

extern "C" void kernel_launch(void* const* d_in, const int* in_sizes, int n_in,
                              void* d_out, int out_size, void* d_ws, size_t ws_size,
                              hipStream_t stream)
{
  (void)in_sizes; (void)n_in; (void)out_size;
  const float* x       = (const float*)d_in[0];
  const float* W_in    = (const float*)d_in[1];
  const float* conv_w  = (const float*)d_in[2];
  const float* conv_b  = (const float*)d_in[3];
  const float* dt_bias = (const float*)d_in[4];
  const float* A_log   = (const float*)d_in[5];
  const float* Dp      = (const float*)d_in[6];
  const float* norm_w  = (const float*)d_in[7];
  const float* W_out   = (const float*)d_in[8];
  float* out = (float*)d_out;

  // ---- batches per pass: footprint(nb) = nb*L_*16320 + 7,385,088 ----
  const int nb = ((size_t)2 * L_ * 16320 + 7385088 <= ws_size) ? 2 : 1;
  const int rows = nb * L_;

  // ---- workspace layout (per-pass buffers) ----
  char* ws = (char*)d_ws;
  unsigned short* zseg = (unsigned short*)ws;  ws += (size_t)rows * DI * 2;   // bf16 z
  unsigned short* xbc  = (unsigned short*)ws;  ws += (size_t)rows * CD * 2;   // bf16 xBC
  _Float16* xs   = (_Float16*)ws;  ws += (size_t)rows * DI * 2;               // fp16 conv-x
  _Float16* ytot = (_Float16*)ws;  ws += (size_t)rows * DI * 2;               // fp16 y
  float* Bm   = (float*)ws;  ws += (size_t)rows * DS * 4;
  float* Cm   = (float*)ws;  ws += (size_t)rows * DS * 4;
  float* dtv  = (float*)ws;  ws += (size_t)rows * H_ * 4;
  float* cumA = (float*)ws;  ws += (size_t)rows * H_ * 4;
  _Float16* Sbuf = (_Float16*)ws;  ws += (size_t)rows * 3072;  // nb*H_*NC*DS*P_*2
  unsigned short* WinT  = (unsigned short*)ws; ws += (size_t)NPJ * DM * 2;
  unsigned short* WoutT = (unsigned short*)ws; ws += (size_t)DM * DI * 2;
  float* WdtT   = (float*)ws;  ws += (size_t)H_ * DM * 4;
  unsigned short* xb    = (unsigned short*)Sbuf;     // overlay: Sbuf dead until k_intra
  unsigned short* ynorm = (unsigned short*)xs;       // overlay: xs dead after k_inter

  k_transpose_cast<<<dim3(24, (NPJ + 31) / 32), 256, 0, stream>>>(W_in, WinT, DM, NPJ);
  k_transpose_cast<<<dim3(48, 24), 256, 0, stream>>>(W_out, WoutT, DI, DM);
  k_wdtT<<<(H_ * DM + 255) / 256, 256, 0, stream>>>(W_in, WdtT);

  for (int b0 = 0; b0 < B_; b0 += nb) {
    const float* xp = x + (size_t)b0 * L_ * DM;

    k_dt2<<<rows / 8, 192, 0, stream>>>(xp, WdtT, dt_bias, dtv, xb);
    // in-proj: wave tile 128x64 -> 0.375 ds_reads/MFMA (was 0.5)
    k_gemm_t<256, 128, 128, 64, true><<<dim3(rows / 256, N1 / 128), 256, 0, stream>>>(
        xb, WinT, zseg, DI, DI, xbc, CD, DM);
    k_conv2<<<dim3(7, rows / CROWS), 256, 0, stream>>>(xbc, conv_w, conv_b, xs, Bm, Cm);
    k_cum<<<(nb * H_ * NC + 255) / 256, 256, 0, stream>>>(dtv, A_log, cumA, nb * H_ * NC);
    k_intra<<<dim3(NC, H_, nb), 256, 0, stream>>>(xs, Bm, Cm, dtv, cumA, ytot, Sbuf);
    k_chunkscan<<<dim3(8, H_, nb), 64, 0, stream>>>(Sbuf, cumA);
    k_inter<<<dim3(NC, H_, nb), 256, 0, stream>>>(xs, Cm, cumA, Sbuf, Dp, ytot);
    k_rms<<<rows, 192, 0, stream>>>(zseg, ytot, norm_w, ynorm);
    // out-proj: block 128x128 -> 0.5 ds_reads/MFMA (was 0.75)
    k_gemm_t<128, 128, 64, 64, false><<<dim3(rows / 128, DM / 128), 256, 0, stream>>>(
        ynorm, WoutT, out + (size_t)b0 * L_ * DM, DM, DM, out + (size_t)b0 * L_ * DM, DM, DI);
  }
}

// Round 3
// 351.548 us; speedup vs baseline: 1.1188x; 1.1188x over previous
//
#include <hip/hip_runtime.h>

// ---- problem constants ----
#define B_   2
#define L_   4096
#define DM   768
#define DI   1536     // D_INNER
#define DS   64       // D_STATE
#define H_   24       // NHEADS
#define P_   64       // HEADDIM
#define CD   1664     // CONV_DIM
#define NPJ  3224     // D_IN_PROJ
#define N1   3200     // GEMM1 useful cols (z + xBC; dt cols done exactly in k_dt2)
#define NPAD 3328     // WinT rows padded to 13 * 256 for the 256-wide N tiles
#define Q_   64       // chunk length
#define NC   64       // chunks per batch
#define SP   76       // LDS row stride (floats) for k_inter tiles
#define HS   72       // fp16 LDS row stride (halves): <=2-way conflicts
#define WDS  772      // k_dt2 LDS W stride
#define CROWS 16      // conv rows per thread

typedef short          bf16x8 __attribute__((ext_vector_type(8)));
typedef _Float16       f16x8  __attribute__((ext_vector_type(8)));
typedef unsigned short us8    __attribute__((ext_vector_type(8)));
typedef unsigned short us4    __attribute__((ext_vector_type(4)));
typedef float          f32x4  __attribute__((ext_vector_type(4)));

__device__ __forceinline__ unsigned short f2bf(float f) {
  unsigned u = __float_as_uint(f);
  u += 0x7fffu + ((u >> 16) & 1u);   // RNE
  return (unsigned short)(u >> 16);
}
__device__ __forceinline__ float bf2f(unsigned short u) {
  return __uint_as_float(((unsigned)u) << 16);
}
__device__ __forceinline__ float siluf(float x) { return x / (1.f + expf(-x)); }
__device__ __forceinline__ float softplusf(float x) { return (x > 20.f) ? x : log1pf(expf(x)); }

// async global->LDS, 16B per lane; LDS dest = uniform base + lane*16
__device__ __forceinline__ void gload16(const unsigned short* g, unsigned short* l) {
  __builtin_amdgcn_global_load_lds(
      (const __attribute__((address_space(1))) void*)g,
      (__attribute__((address_space(3))) void*)l, 16, 0, 0);
}

// ---------------- transpose + cast (R x C fp32) -> (C x R bf16) ----------------
__global__ __launch_bounds__(256)
void k_transpose_cast(const float* __restrict__ src, unsigned short* __restrict__ dst,
                      int R, int C)
{
  __shared__ float tile[32][33];
  const int tx = threadIdx.x & 31, ty = threadIdx.x >> 5;
  const int r0 = blockIdx.x * 32, c0 = blockIdx.y * 32;
#pragma unroll
  for (int r = 0; r < 4; ++r) {
    int rr = r0 + ty + r * 8, cc = c0 + tx;
    if (rr < R && cc < C) tile[ty + r * 8][tx] = src[(size_t)rr * C + cc];
  }
  __syncthreads();
#pragma unroll
  for (int r = 0; r < 4; ++r) {
    int orow = c0 + ty + r * 8, ocol = r0 + tx;
    if (orow < C && ocol < R) dst[(size_t)orow * R + ocol] = f2bf(tile[tx][ty + r * 8]);
  }
}

// ---------------- gather dt columns of W_in -> contiguous fp32 WdtT[24][768] ----------------
__global__ void k_wdtT(const float* __restrict__ W_in, float* __restrict__ WdtT)
{
  const int idx = blockIdx.x * 256 + threadIdx.x;
  if (idx >= H_ * DM) return;
  const int k = idx / H_, h = idx % H_;
  WdtT[(size_t)h * DM + k] = W_in[(size_t)k * NPJ + N1 + h];
}

// ---------------- bf16 MFMA GEMM, BK=64, XOR-swizzled LDS (conflict-free) ----------------
// (out-projection; proven config from the 347us baseline)
template<int BM, int BN, int WM, int WN, bool OUT_BF16>
__global__ __launch_bounds__(256)
void k_gemm_t(const unsigned short* __restrict__ A, const unsigned short* __restrict__ Bt,
              void* __restrict__ C0v, int ld0, int ncol0,
              void* __restrict__ C1v, int ld1, int K)
{
  constexpr int MI = WM / 16, NI = WN / 16;
  constexpr int WAVES_N = BN / WN;
  constexpr int RA = BM / 32, RB = BN / 32;
  const int m0 = blockIdx.x * BM, n0 = blockIdx.y * BN;
  __shared__ unsigned short As[BM][64];
  __shared__ unsigned short Bs[BN][64];
  const int tid  = threadIdx.x;
  const int wave = tid >> 6, lane = tid & 63;
  const int quad = lane >> 4, r16 = lane & 15;
  const int wm = (wave / WAVES_N) * WM, wn = (wave % WAVES_N) * WN;

  const int lr8 = lane >> 3;                                // 0..7 row-in-band
  const int csw = ((lane & 7) ^ lr8) * 8;                   // swizzled source col (shorts)
  const unsigned short* gA = A  + (size_t)(m0 + wave * 8 + lr8) * K + csw;
  const unsigned short* gB = Bt + (size_t)(n0 + wave * 8 + lr8) * K + csw;
  unsigned short* lA = &As[wave * 8][0] + (size_t)lane * 8; // +lane*16B
  unsigned short* lB = &Bs[wave * 8][0] + (size_t)lane * 8;

  f32x4 acc[MI][NI];
#pragma unroll
  for (int mi = 0; mi < MI; ++mi)
#pragma unroll
    for (int ni = 0; ni < NI; ++ni) acc[mi][ni] = (f32x4){0.f, 0.f, 0.f, 0.f};

  for (int k0 = 0; k0 < K; k0 += 64) {
#pragma unroll
    for (int r = 0; r < RA; ++r)
      gload16(gA + (size_t)(r * 32) * K + k0, lA + (size_t)r * 32 * 64);
#pragma unroll
    for (int r = 0; r < RB; ++r)
      gload16(gB + (size_t)(r * 32) * K + k0, lB + (size_t)r * 32 * 64);
    __syncthreads();
    bf16x8 af[MI][2], bfr[NI][2];
#pragma unroll
    for (int mi = 0; mi < MI; ++mi)
#pragma unroll
      for (int ks = 0; ks < 2; ++ks)
        af[mi][ks] = *(const bf16x8*)&As[wm + mi * 16 + r16][((quad + ks * 4) ^ (r16 & 7)) * 8];
#pragma unroll
    for (int ni = 0; ni < NI; ++ni)
#pragma unroll
      for (int ks = 0; ks < 2; ++ks)
        bfr[ni][ks] = *(const bf16x8*)&Bs[wn + ni * 16 + r16][((quad + ks * 4) ^ (r16 & 7)) * 8];
#pragma unroll
    for (int mi = 0; mi < MI; ++mi)
#pragma unroll
      for (int ni = 0; ni < NI; ++ni)
#pragma unroll
        for (int ks = 0; ks < 2; ++ks)
          acc[mi][ni] = __builtin_amdgcn_mfma_f32_16x16x32_bf16(
              af[mi][ks], bfr[ni][ks], acc[mi][ni], 0, 0, 0);
    __syncthreads();
  }
#pragma unroll
  for (int mi = 0; mi < MI; ++mi)
#pragma unroll
    for (int ni = 0; ni < NI; ++ni) {
      int col = n0 + wn + ni * 16 + r16;
      void* dst; int ld, c;
      if (col < ncol0) { dst = C0v; ld = ld0; c = col; }
      else             { dst = C1v; ld = ld1; c = col - ncol0; }
#pragma unroll
      for (int r = 0; r < 4; ++r) {
        int row = m0 + wm + mi * 16 + quad * 4 + r;
        if (OUT_BF16) ((unsigned short*)dst)[(size_t)row * ld + c] = f2bf(acc[mi][ni][r]);
        else          ((float*)dst)[(size_t)row * ld + c] = acc[mi][ni][r];
      }
    }
}

// ---------------- 256x256 8-phase pipelined bf16 GEMM (T2+T3+T4+T5) ----------------
// v2: Gray-code operand reuse. r1 failure isolated to 12 ds_read_b128/phase
// (0.75 reads/MFMA, LDS-read-bound: MfmaUtil ratio 16.4/27.7 matched traffic ratio).
// Now: per-phase loads = {12,4,8,0 | 12,4,8,0} -> avg 6 (0.375 reads/MFMA).
// paf = current A-half frags (reloaded when MH or BUF changes);
// pbf[2] = BOTH B-half frag sets of current buffer (reloaded when BUF changes or
// that half first appears). Stage schedule / vmcnt(4) placement / swizzle = r1
// verbatim (correctness-proven); register holding only moves LDS reads EARLIER,
// so every WAR constraint is relaxed and all RAW waits are unchanged.
template<bool OUT_BF16>
__global__ __launch_bounds__(512)
void k_gemm8(const unsigned short* __restrict__ A, const unsigned short* __restrict__ Bt,
             void* __restrict__ C0v, int ld0, int ncol0,
             void* __restrict__ C1v, int ld1, int K, int ntot)
{
  __shared__ unsigned short As_s[2][2][128][64];
  __shared__ unsigned short Bs_s[2][2][128][64];
  const int m0 = blockIdx.x * 256, n0 = blockIdx.y * 256;
  const int tid = threadIdx.x;
  const int wave = tid >> 6, lane = tid & 63;
  const int quad = lane >> 4, r16 = lane & 15;
  const int wr = wave >> 2, wc = wave & 3;
  const int KT = K >> 6;                     // 64-wide K tiles (even, >=2)

  const int lr8 = lane >> 3;                 // row within the 8-row band of one gload
  const int csw = ((lane & 7) ^ lr8) * 8;    // pre-swizzled source col (shorts)
  const unsigned short* gA = A  + (size_t)(m0 + wave * 16 + lr8) * K + csw;
  const unsigned short* gB = Bt + (size_t)(n0 + wave * 16 + lr8) * K + csw;

  // one stage = one 128x64 half-tile = 2 gload instructions per thread (16 rows/wave)
  auto stA = [&](int buf, int half, int kt) {
    const unsigned short* src = gA + (size_t)(half * 128) * K + (size_t)kt * 64;
    unsigned short* dst = &As_s[buf][half][wave * 16][0] + lane * 8;
    gload16(src, dst);
    gload16(src + (size_t)8 * K, dst + 512);
  };
  auto stB = [&](int buf, int half, int kt) {
    const unsigned short* src = gB + (size_t)(half * 128) * K + (size_t)kt * 64;
    unsigned short* dst = &Bs_s[buf][half][wave * 16][0] + lane * 8;
    gload16(src, dst);
    gload16(src + (size_t)8 * K, dst + 512);
  };

  f32x4 acc[8][4];
#pragma unroll
  for (int mi = 0; mi < 8; ++mi)
#pragma unroll
    for (int ni = 0; ni < 4; ++ni) acc[mi][ni] = (f32x4){0.f, 0.f, 0.f, 0.f};

  bf16x8 paf[4][2];        // current A-half fragments
  bf16x8 pbf[2][2][2];     // [half][ni][ks] B fragments of current buffer

  // prologue: tile0 fully + tile1 halves A0,B1; drain tile0 (8 instrs), leave 2 stages
  stA(0, 0, 0); stB(0, 0, 0); stA(0, 1, 0); stB(0, 1, 0);
  stA(1, 0, 1); stB(1, 1, 1);
  asm volatile("s_waitcnt vmcnt(4)" ::: "memory");
  __builtin_amdgcn_s_barrier();

#define DO_PHASE(MH, NH, BUF, LDA_, LDB_, STAGE, VMW)                              \
  {                                                                                \
    if (LDA_) {                                                                    \
      _Pragma("unroll") for (int mi2 = 0; mi2 < 4; ++mi2)                          \
        _Pragma("unroll") for (int ks = 0; ks < 2; ++ks)                           \
          paf[mi2][ks] = *(const bf16x8*)&As_s[BUF][MH]                            \
              [wr * 16 + mi2 * 32 + r16][((quad + ks * 4) ^ (r16 & 7)) * 8];       \
    }                                                                              \
    if (LDB_) {                                                                    \
      _Pragma("unroll") for (int ni2 = 0; ni2 < 2; ++ni2)                          \
        _Pragma("unroll") for (int ks = 0; ks < 2; ++ks)                           \
          pbf[NH][ni2][ks] = *(const bf16x8*)&Bs_s[BUF][NH]                        \
              [wc * 16 + ni2 * 64 + r16][((quad + ks * 4) ^ (r16 & 7)) * 8];       \
    }                                                                              \
    STAGE;                                                                         \
    VMW;                                                                           \
    __builtin_amdgcn_s_barrier();                                                  \
    asm volatile("s_waitcnt lgkmcnt(0)" ::: "memory");                             \
    __builtin_amdgcn_sched_barrier(0);                                             \
    __builtin_amdgcn_s_setprio(1);                                                 \
    _Pragma("unroll") for (int mi2 = 0; mi2 < 4; ++mi2)                            \
      _Pragma("unroll") for (int ni2 = 0; ni2 < 2; ++ni2)                          \
        _Pragma("unroll") for (int ks = 0; ks < 2; ++ks)                           \
          acc[(MH) * 4 + mi2][(NH) * 2 + ni2] =                                    \
              __builtin_amdgcn_mfma_f32_16x16x32_bf16(                             \
                  paf[mi2][ks], pbf[NH][ni2][ks],                                  \
                  acc[(MH) * 4 + mi2][(NH) * 2 + ni2], 0, 0, 0);                   \
    __builtin_amdgcn_s_setprio(0);                                                 \
    __builtin_amdgcn_sched_barrier(0);                                             \
    __builtin_amdgcn_s_barrier();                                                  \
  }

  const int NIT = KT >> 1;
  for (int it = 0; it < NIT; ++it) {
    const int t  = it * 2;
    const int t2 = (t + 2 < KT) ? t + 2 : KT - 1;   // clamp: keep vmcnt counts exact
    const int t3 = (t + 3 < KT) ? t + 3 : KT - 1;
    DO_PHASE(0, 0, 0, 1, 1, stA(1, 1, t + 1), (void)0);
    DO_PHASE(0, 1, 0, 0, 1, stB(1, 0, t + 1), (void)0);
    DO_PHASE(1, 1, 0, 1, 0, stA(0, 0, t2),    (void)0);
    DO_PHASE(1, 0, 0, 0, 0, stB(0, 1, t2),
             asm volatile("s_waitcnt vmcnt(4)" ::: "memory"));
    DO_PHASE(0, 0, 1, 1, 1, stB(0, 0, t2),    (void)0);
    DO_PHASE(0, 1, 1, 0, 1, stA(0, 1, t2),    (void)0);
    DO_PHASE(1, 1, 1, 1, 0, stA(1, 0, t3),    (void)0);
    DO_PHASE(1, 0, 1, 0, 0, stB(1, 1, t3),
             asm volatile("s_waitcnt vmcnt(4)" ::: "memory"));
  }
#undef DO_PHASE

#pragma unroll
  for (int mi = 0; mi < 8; ++mi)
#pragma unroll
    for (int ni = 0; ni < 4; ++ni) {
      const int col = n0 + wc * 16 + (ni & 1) * 64 + (ni >> 1) * 128 + r16;
      // NOTE: acc[mi][ni] was indexed as [MH*4+mi2][NH*2+ni2]; invert:
      // ni = NH*2+ni2 -> NH = ni>>1, ni2 = ni&1 -> col offset = NH*128 + ni2*64. OK.
      if (col >= ntot) continue;                    // N-edge guard (padded last tile)
      void* dst; int ld, c;
      if (col < ncol0) { dst = C0v; ld = ld0; c = col; }
      else             { dst = C1v; ld = ld1; c = col - ncol0; }
#pragma unroll
      for (int r = 0; r < 4; ++r) {
        const int row = m0 + wr * 16 + (mi & 3) * 32 + (mi >> 2) * 128 + quad * 4 + r;
        if (OUT_BF16) ((unsigned short*)dst)[(size_t)row * ld + c] = f2bf(acc[mi][ni][r]);
        else          ((float*)dst)[(size_t)row * ld + c] = acc[mi][ni][r];
      }
    }
}

// ---------------- depthwise conv(4) + silu: sliding window, batch-boundary aware ----------------
__global__ __launch_bounds__(256)
void k_conv2(const unsigned short* __restrict__ xbc, const float* __restrict__ cw,
             const float* __restrict__ cb, _Float16* __restrict__ xs,
             float* __restrict__ Bm, float* __restrict__ Cm)
{
  const int ch = blockIdx.x * 256 + threadIdx.x;
  if (ch >= CD) return;
  const int r0 = blockIdx.y * CROWS;
  const float w0 = cw[ch * 4], w1 = cw[ch * 4 + 1], w2 = cw[ch * 4 + 2], w3 = cw[ch * 4 + 3];
  const float bias = cb[ch];
  float a, b, c;
  if ((r0 & (L_ - 1)) == 0) {                 // batch start: zero history
    a = 0.f; b = 0.f; c = 0.f;
  } else {
    a = bf2f(xbc[(size_t)(r0 - 3) * CD + ch]);
    b = bf2f(xbc[(size_t)(r0 - 2) * CD + ch]);
    c = bf2f(xbc[(size_t)(r0 - 1) * CD + ch]);
  }
#pragma unroll
  for (int i = 0; i < CROWS; ++i) {
    const int lr = r0 + i;
    float d = bf2f(xbc[(size_t)lr * CD + ch]);
    float v = siluf(bias + a * w0 + b * w1 + c * w2 + d * w3);
    a = b; b = c; c = d;
    if (ch < DI)           xs[(size_t)lr * DI + ch] = (_Float16)v;
    else if (ch < DI + DS) Bm[(size_t)lr * DS + (ch - DI)] = v;
    else                   Cm[(size_t)lr * DS + (ch - DI - DS)] = v;
  }
}

// ---------------- exact fp32 dt via LDS-staged WdtT + fused x->bf16 cast ----------------
// block = 192 threads = 24 heads x 8 rows; thread h also casts x chunk [h*32,h*32+32)
__global__ __launch_bounds__(192)
void k_dt2(const float* __restrict__ x, const float* __restrict__ WdtT,
           const float* __restrict__ dt_bias, float* __restrict__ dtv,
           unsigned short* __restrict__ xb)
{
  __shared__ float sW[H_][WDS];
  for (int i = threadIdx.x; i < H_ * DM; i += 192)
    sW[i / DM][i % DM] = WdtT[i];
  const int h = threadIdx.x % H_, rloc = threadIdx.x / H_;
  const int lrow = blockIdx.x * 8 + rloc;
  const float* xr = x + (size_t)lrow * DM;
  __syncthreads();
  float acc = 0.f;
#pragma unroll 8
  for (int k = 0; k < DM; k += 4) {
    f32x4 xv = *(const f32x4*)(xr + k);
    f32x4 wv = *(const f32x4*)&sW[h][k];
    acc += xv[0] * wv[0] + xv[1] * wv[1] + xv[2] * wv[2] + xv[3] * wv[3];
  }
  dtv[(size_t)lrow * H_ + h] = softplusf(acc + dt_bias[h]);
  // fused cast: 32-elem chunk per thread (L1-hot re-read)
  const float* xi = xr + h * 32;
  unsigned short* xo = xb + (size_t)lrow * DM + h * 32;
#pragma unroll
  for (int j = 0; j < 32; j += 8) {
    f32x4 a = *(const f32x4*)(xi + j);
    f32x4 b = *(const f32x4*)(xi + j + 4);
    us8 o;
#pragma unroll
    for (int e = 0; e < 4; ++e) { o[e] = f2bf(a[e]); o[e + 4] = f2bf(b[e]); }
    *(us8*)(xo + j) = o;
  }
}

// ---------------- per-chunk inclusive cumsum of dt*A ----------------
__global__ void k_cum(const float* __restrict__ dtv, const float* __restrict__ A_log,
                      float* __restrict__ cumA, int n)
{
  const int idx = blockIdx.x * 256 + threadIdx.x;      // ((bz*H+h)*NC + c)
  if (idx >= n) return;
  const int c = idx % NC;
  const int h = (idx / NC) % H_;
  const int bz = idx / (NC * H_);
  const float A = -expf(A_log[h]);
  float cum = 0.f;
  const int rowbase = bz * L_ + c * Q_;
  float* outp = cumA + (size_t)idx * Q_;
  for (int i = 0; i < Q_; ++i) {
    cum += dtv[(size_t)(rowbase + i) * H_ + h] * A;
    outp[i] = cum;
  }
}

// ---------------- intra-chunk via fp16 MFMA; ytot/Sbuf stored fp16 ----------------
__global__ __launch_bounds__(256)
void k_intra(const _Float16* __restrict__ xs, const float* __restrict__ Bm,
             const float* __restrict__ Cm, const float* __restrict__ dtv,
             const float* __restrict__ cumA, _Float16* __restrict__ ytot,
             _Float16* __restrict__ Sbuf)
{
  const int c = blockIdx.x, h = blockIdx.y, bz = blockIdx.z;
  const int gidx = (bz * H_ + h) * NC + c;
  __shared__ _Float16 sCW[Q_][HS];   // C, then W
  __shared__ _Float16 sB [Q_][HS];
  __shared__ _Float16 sBT[Q_][HS];   // (coef_j * B[j][n]) transposed -> [n][j]
  __shared__ _Float16 sXT[Q_][HS];   // X transposed -> [p][j]
  __shared__ float scum[Q_], sdt[Q_];
  const int tid = threadIdx.x;
  const int rowbase = bz * L_ + c * Q_;

  {
    const int j = tid >> 2, s16 = (tid & 3) * 16;
    if (tid < Q_) {
      scum[tid] = cumA[(size_t)gidx * Q_ + tid];
      sdt[tid]  = dtv[(size_t)(rowbase + tid) * H_ + h];
    }
    const _Float16* xsrc = xs + (size_t)(rowbase + j) * DI + h * P_ + s16;
    f16x8 xv0 = *(const f16x8*)xsrc;
    f16x8 xv1 = *(const f16x8*)(xsrc + 8);
    f32x4 bv[4], cv[4];
    const float* bsrc = Bm + (size_t)(rowbase + j) * DS + s16;
    const float* csrc = Cm + (size_t)(rowbase + j) * DS + s16;
#pragma unroll
    for (int q = 0; q < 4; ++q) {
      bv[q] = *(const f32x4*)(bsrc + q * 4);
      cv[q] = *(const f32x4*)(csrc + q * 4);
    }
    __syncthreads();
    const float coef = expf(scum[Q_ - 1] - scum[j]) * sdt[j];
    union { f16x8 v; _Float16 e[8]; } pc[2], pb[2];
#pragma unroll
    for (int q = 0; q < 4; ++q)
#pragma unroll
      for (int e = 0; e < 4; ++e) {
        int o = q * 4 + e;
        pc[o >> 3].e[o & 7] = (_Float16)cv[q][e];
        pb[o >> 3].e[o & 7] = (_Float16)bv[q][e];
        sBT[s16 + o][j] = (_Float16)(bv[q][e] * coef);
        sXT[s16 + o][j] = (o < 8) ? xv0[o] : xv1[o - 8];
      }
    *(f16x8*)&sCW[j][s16]     = pc[0].v;
    *(f16x8*)&sCW[j][s16 + 8] = pc[1].v;
    *(f16x8*)&sB [j][s16]     = pb[0].v;
    *(f16x8*)&sB [j][s16 + 8] = pb[1].v;
  }
  __syncthreads();

  const int wave = tid >> 6, lane = tid & 63;
  const int quad = lane >> 4, r16 = lane & 15;
  const int i0 = wave * 16;
  const int irow = i0 + quad * 4;

  f32x4 g[4];
#pragma unroll
  for (int q = 0; q < 4; ++q) g[q] = (f32x4){0.f, 0.f, 0.f, 0.f};
#pragma unroll
  for (int ni = 0; ni < 4; ++ni) {
    if (ni <= wave) {
#pragma unroll
      for (int ks = 0; ks < 2; ++ks)
        g[ni] = __builtin_amdgcn_mfma_f32_16x16x32_f16(
            *(const f16x8*)&sCW[i0 + r16][ks * 32 + quad * 8],
            *(const f16x8*)&sB [ni * 16 + r16][ks * 32 + quad * 8], g[ni], 0, 0, 0);
    }
  }
  float wv[4][4];
#pragma unroll
  for (int ni = 0; ni < 4; ++ni)
#pragma unroll
    for (int r = 0; r < 4; ++r) {
      int i = irow + r, jcol = ni * 16 + r16;
      float v = 0.f;
      if (ni <= wave && jcol <= i)
        v = g[ni][r] * expf(scum[i] - scum[jcol]) * sdt[jcol];
      wv[ni][r] = v;
    }
  __syncthreads();
#pragma unroll
  for (int ni = 0; ni < 4; ++ni)
#pragma unroll
    for (int r = 0; r < 4; ++r)
      sCW[irow + r][ni * 16 + r16] = (_Float16)wv[ni][r];
  __syncthreads();

  f32x4 y[4];
#pragma unroll
  for (int q = 0; q < 4; ++q) y[q] = (f32x4){0.f, 0.f, 0.f, 0.f};
#pragma unroll
  for (int ni = 0; ni < 4; ++ni)
#pragma unroll
    for (int ks = 0; ks < 2; ++ks) {
      if (ks == 0 || wave >= 2)
        y[ni] = __builtin_amdgcn_mfma_f32_16x16x32_f16(
            *(const f16x8*)&sCW[i0 + r16][ks * 32 + quad * 8],
            *(const f16x8*)&sXT[ni * 16 + r16][ks * 32 + quad * 8], y[ni], 0, 0, 0);
    }
#pragma unroll
  for (int ni = 0; ni < 4; ++ni)
#pragma unroll
    for (int r = 0; r < 4; ++r)
      ytot[(size_t)(rowbase + irow + r) * DI + h * P_ + ni * 16 + r16] = (_Float16)y[ni][r];

  f32x4 t4[4];
#pragma unroll
  for (int q = 0; q < 4; ++q) t4[q] = (f32x4){0.f, 0.f, 0.f, 0.f};
#pragma unroll
  for (int ni = 0; ni < 4; ++ni)
#pragma unroll
    for (int ks = 0; ks < 2; ++ks)
      t4[ni] = __builtin_amdgcn_mfma_f32_16x16x32_f16(
          *(const f16x8*)&sBT[i0 + r16][ks * 32 + quad * 8],
          *(const f16x8*)&sXT[ni * 16 + r16][ks * 32 + quad * 8], t4[ni], 0, 0, 0);
  _Float16* sp = Sbuf + (size_t)gidx * (DS * P_);
#pragma unroll
  for (int ni = 0; ni < 4; ++ni)
#pragma unroll
    for (int r = 0; r < 4; ++r)
      sp[(irow + r) * P_ + ni * 16 + r16] = (_Float16)t4[ni][r];
}

// ---------------- sequential inter-chunk recurrence (in-place, fp16 storage) ----------------
__global__ void k_chunkscan(_Float16* __restrict__ Sbuf, const float* __restrict__ cumA)
{
  const int seg = blockIdx.x, h = blockIdx.y, bz = blockIdx.z;
  const int bh = bz * H_ + h;
  __shared__ float dec[NC];
  const int tid = threadIdx.x;
  if (tid < NC) dec[tid] = expf(cumA[((size_t)(bh * NC + tid)) * Q_ + (Q_ - 1)]);
  __syncthreads();
  const size_t off = (size_t)seg * 512 + (size_t)tid * 8;
  float s[8];
#pragma unroll
  for (int e = 0; e < 8; ++e) s[e] = 0.f;
  size_t base = (size_t)bh * NC * (DS * P_) + off;
  for (int c = 0; c < NC; ++c) {
    _Float16* p = Sbuf + base + (size_t)c * (DS * P_);
    f16x8 v = *(const f16x8*)p;
    f16x8 sto;
#pragma unroll
    for (int e = 0; e < 8; ++e) sto[e] = (_Float16)s[e];
    *(f16x8*)p = sto;                    // store state BEFORE chunk c
    const float d = dec[c];
#pragma unroll
    for (int e = 0; e < 8; ++e) s[e] = s[e] * d + (float)v[e];
  }
}

// ---------------- inter-chunk correction + D*x (ytot fp16 RMW) ----------------
__global__ __launch_bounds__(256)
void k_inter(const _Float16* __restrict__ xs, const float* __restrict__ Cm,
             const float* __restrict__ cumA, const _Float16* __restrict__ Sbuf,
             const float* __restrict__ Dp, _Float16* __restrict__ ytot)
{
  const int c = blockIdx.x, h = blockIdx.y, bz = blockIdx.z;
  const int gidx = (bz * H_ + h) * NC + c;
  __shared__ float sS[DS][SP];
  __shared__ float sC[Q_][SP];
  __shared__ float scum[Q_];
  const int tid = threadIdx.x;
  const int jr = tid >> 2, blk = (tid & 3) * 16;
  const int rowbase = bz * L_ + c * Q_;
  {
    const _Float16* ssrc = Sbuf + (size_t)gidx * (DS * P_) + jr * P_ + blk;
    f16x8 sv0 = *(const f16x8*)ssrc;
    f16x8 sv1 = *(const f16x8*)(ssrc + 8);
    const float* csrc = Cm + (size_t)(rowbase + jr) * DS + blk;
#pragma unroll
    for (int o = 0; o < 8; ++o) {
      sS[jr][blk + o]     = (float)sv0[o];
      sS[jr][blk + 8 + o] = (float)sv1[o];
    }
#pragma unroll
    for (int q = 0; q < 4; ++q)
      *(f32x4*)&sC[jr][blk + q * 4] = *(const f32x4*)(csrc + q * 4);
    if (tid < Q_) scum[tid] = cumA[(size_t)gidx * Q_ + tid];
  }
  __syncthreads();
  const int i = jr;
  f32x4 acc[4];
#pragma unroll
  for (int q = 0; q < 4; ++q) acc[q] = (f32x4){0.f, 0.f, 0.f, 0.f};
  for (int n = 0; n < DS; ++n) {
    float cv = sC[i][n];
#pragma unroll
    for (int q = 0; q < 4; ++q) acc[q] += cv * *(const f32x4*)&sS[n][blk + q * 4];
  }
  const float e = expf(scum[i]);
  const float Dh = Dp[h];
  _Float16* yt = ytot + (size_t)(rowbase + i) * DI + h * P_ + blk;
  const _Float16* xsr = xs + (size_t)(rowbase + i) * DI + h * P_ + blk;
  f16x8 xa = *(const f16x8*)xsr;
  f16x8 xb2 = *(const f16x8*)(xsr + 8);
  f16x8 y0 = *(const f16x8*)yt;
  f16x8 y1 = *(const f16x8*)(yt + 8);
#pragma unroll
  for (int o = 0; o < 16; ++o) {
    float cur = (float)((o < 8) ? y0[o] : y1[o - 8]);
    float xf  = (float)((o < 8) ? xa[o] : xb2[o - 8]);
    cur += e * acc[o >> 2][o & 3] + Dh * xf;
    if (o < 8) y0[o] = (_Float16)cur; else y1[o - 8] = (_Float16)cur;
  }
  *(f16x8*)yt = y0;
  *(f16x8*)(yt + 8) = y1;
}

// ---------------- gate (silu(z)) + RMSNorm + cast bf16 ----------------
__global__ __launch_bounds__(192)
void k_rms(const unsigned short* __restrict__ z, const _Float16* __restrict__ ytot,
           const float* __restrict__ norm_w, unsigned short* __restrict__ ynorm)
{
  const int row = blockIdx.x, tid = threadIdx.x;
  const int e0 = tid * 8;
  us8 zv = *(const us8*)(z + (size_t)row * DI + e0);
  f16x8 yv = *(const f16x8*)(ytot + (size_t)row * DI + e0);
  float g[8];
  float ss = 0.f;
#pragma unroll
  for (int q = 0; q < 8; ++q) {
    g[q] = (float)yv[q] * siluf(bf2f(zv[q]));
    ss += g[q] * g[q];
  }
#pragma unroll
  for (int off = 32; off > 0; off >>= 1) ss += __shfl_down(ss, off);
  __shared__ float wsum[3];
  __shared__ float sscale;
  if ((tid & 63) == 0) wsum[tid >> 6] = ss;
  __syncthreads();
  if (tid == 0) sscale = rsqrtf((wsum[0] + wsum[1] + wsum[2]) * (1.f / DI) + 1e-5f);
  __syncthreads();
  const float sc = sscale;
  us8 o;
#pragma unroll
  for (int q = 0; q < 8; ++q) o[q] = f2bf(g[q] * sc * norm_w[e0 + q]);
  *(us8*)(ynorm + (size_t)row * DI + e0) = o;
}

extern "C" void kernel_launch(void* const* d_in, const int* in_sizes, int n_in,
                              void* d_out, int out_size, void* d_ws, size_t ws_size,
                              hipStream_t stream)
{
  (void)in_sizes; (void)n_in; (void)out_size;
  const float* x       = (const float*)d_in[0];
  const float* W_in    = (const float*)d_in[1];
  const float* conv_w  = (const float*)d_in[2];
  const float* conv_b  = (const float*)d_in[3];
  const float* dt_bias = (const float*)d_in[4];
  const float* A_log   = (const float*)d_in[5];
  const float* Dp      = (const float*)d_in[6];
  const float* norm_w  = (const float*)d_in[7];
  const float* W_out   = (const float*)d_in[8];
  float* out = (float*)d_out;

  // ---- batches per pass: footprint(nb) = nb*L_*16320 + 7,544,832 ----
  const int nb = ((size_t)2 * L_ * 16320 + 7544832 <= ws_size) ? 2 : 1;
  const int rows = nb * L_;

  // ---- workspace layout (per-pass buffers) ----
  char* ws = (char*)d_ws;
  unsigned short* zseg = (unsigned short*)ws;  ws += (size_t)rows * DI * 2;   // bf16 z
  unsigned short* xbc  = (unsigned short*)ws;  ws += (size_t)rows * CD * 2;   // bf16 xBC
  _Float16* xs   = (_Float16*)ws;  ws += (size_t)rows * DI * 2;               // fp16 conv-x
  _Float16* ytot = (_Float16*)ws;  ws += (size_t)rows * DI * 2;               // fp16 y
  float* Bm   = (float*)ws;  ws += (size_t)rows * DS * 4;
  float* Cm   = (float*)ws;  ws += (size_t)rows * DS * 4;
  float* dtv  = (float*)ws;  ws += (size_t)rows * H_ * 4;
  float* cumA = (float*)ws;  ws += (size_t)rows * H_ * 4;
  _Float16* Sbuf = (_Float16*)ws;  ws += (size_t)rows * 3072;  // nb*H_*NC*DS*P_*2
  unsigned short* WinT  = (unsigned short*)ws; ws += (size_t)NPAD * DM * 2;   // padded to 3328 rows
  unsigned short* WoutT = (unsigned short*)ws; ws += (size_t)DM * DI * 2;
  float* WdtT   = (float*)ws;  ws += (size_t)H_ * DM * 4;
  unsigned short* xb    = (unsigned short*)Sbuf;     // overlay: Sbuf dead until k_intra
  unsigned short* ynorm = (unsigned short*)xs;       // overlay: xs dead after k_inter

  k_transpose_cast<<<dim3(24, (NPJ + 31) / 32), 256, 0, stream>>>(W_in, WinT, DM, NPJ);
  k_transpose_cast<<<dim3(48, 24), 256, 0, stream>>>(W_out, WoutT, DI, DM);
  k_wdtT<<<(H_ * DM + 255) / 256, 256, 0, stream>>>(W_in, WdtT);

  for (int b0 = 0; b0 < B_; b0 += nb) {
    const float* xp = x + (size_t)b0 * L_ * DM;

    k_dt2<<<rows / 8, 192, 0, stream>>>(xp, WdtT, dt_bias, dtv, xb);
    k_gemm8<true><<<dim3(rows / 256, (N1 + 255) / 256), 512, 0, stream>>>(
        xb, WinT, zseg, DI, DI, xbc, CD, DM, N1);
    k_conv2<<<dim3(7, rows / CROWS), 256, 0, stream>>>(xbc, conv_w, conv_b, xs, Bm, Cm);
    k_cum<<<(nb * H_ * NC + 255) / 256, 256, 0, stream>>>(dtv, A_log, cumA, nb * H_ * NC);
    k_intra<<<dim3(NC, H_, nb), 256, 0, stream>>>(xs, Bm, Cm, dtv, cumA, ytot, Sbuf);
    k_chunkscan<<<dim3(8, H_, nb), 64, 0, stream>>>(Sbuf, cumA);
    k_inter<<<dim3(NC, H_, nb), 256, 0, stream>>>(xs, Cm, cumA, Sbuf, Dp, ytot);
    k_rms<<<rows, 192, 0, stream>>>(zseg, ytot, norm_w, ynorm);
    k_gemm_t<128, 64, 64, 32, false><<<dim3(rows / 128, DM / 64), 256, 0, stream>>>(
        ynorm, WoutT, out + (size_t)b0 * L_ * DM, DM, DM, out + (size_t)b0 * L_ * DM, DM, DI);
  }
}

// Round 4
// 350.357 us; speedup vs baseline: 1.1226x; 1.0034x over previous
//
#include <hip/hip_runtime.h>

// ---- problem constants ----
#define B_   2
#define L_   4096
#define DM   768
#define DI   1536     // D_INNER
#define DS   64       // D_STATE
#define H_   24       // NHEADS
#define P_   64       // HEADDIM
#define CD   1664     // CONV_DIM
#define NPJ  3224     // D_IN_PROJ
#define N1   3200     // GEMM1 useful cols (z + xBC; dt cols done exactly in k_dt2)
#define Q_   64       // chunk length
#define NC   64       // chunks per batch
#define SP   76       // LDS row stride (floats) for k_inter tiles
#define HS   72       // fp16 LDS row stride (halves): <=2-way conflicts
#define WDS  772      // k_dt2 LDS W stride
#define CROWS 16      // conv rows per thread

typedef short          bf16x8 __attribute__((ext_vector_type(8)));
typedef _Float16       f16x8  __attribute__((ext_vector_type(8)));
typedef unsigned short us8    __attribute__((ext_vector_type(8)));
typedef unsigned short us4    __attribute__((ext_vector_type(4)));
typedef float          f32x4  __attribute__((ext_vector_type(4)));

__device__ __forceinline__ unsigned short f2bf(float f) {
  unsigned u = __float_as_uint(f);
  u += 0x7fffu + ((u >> 16) & 1u);   // RNE
  return (unsigned short)(u >> 16);
}
__device__ __forceinline__ float bf2f(unsigned short u) {
  return __uint_as_float(((unsigned)u) << 16);
}
__device__ __forceinline__ float siluf(float x) { return x / (1.f + expf(-x)); }
__device__ __forceinline__ float softplusf(float x) { return (x > 20.f) ? x : log1pf(expf(x)); }

// async global->LDS, 16B per lane; LDS dest = uniform base + lane*16
__device__ __forceinline__ void gload16(const unsigned short* g, unsigned short* l) {
  __builtin_amdgcn_global_load_lds(
      (const __attribute__((address_space(1))) void*)g,
      (__attribute__((address_space(3))) void*)l, 16, 0, 0);
}

// ---------------- transpose + cast (R x C fp32) -> (C x R bf16) ----------------
__global__ __launch_bounds__(256)
void k_transpose_cast(const float* __restrict__ src, unsigned short* __restrict__ dst,
                      int R, int C)
{
  __shared__ float tile[32][33];
  const int tx = threadIdx.x & 31, ty = threadIdx.x >> 5;
  const int r0 = blockIdx.x * 32, c0 = blockIdx.y * 32;
#pragma unroll
  for (int r = 0; r < 4; ++r) {
    int rr = r0 + ty + r * 8, cc = c0 + tx;
    if (rr < R && cc < C) tile[ty + r * 8][tx] = src[(size_t)rr * C + cc];
  }
  __syncthreads();
#pragma unroll
  for (int r = 0; r < 4; ++r) {
    int orow = c0 + ty + r * 8, ocol = r0 + tx;
    if (orow < C && ocol < R) dst[(size_t)orow * R + ocol] = f2bf(tile[tx][ty + r * 8]);
  }
}

// ---------------- gather dt columns of W_in -> contiguous fp32 WdtT[24][768] ----------------
__global__ void k_wdtT(const float* __restrict__ W_in, float* __restrict__ WdtT)
{
  const int idx = blockIdx.x * 256 + threadIdx.x;
  if (idx >= H_ * DM) return;
  const int k = idx / H_, h = idx % H_;
  WdtT[(size_t)h * DM + k] = W_in[(size_t)k * NPJ + N1 + h];
}

// ---------------- bf16 MFMA GEMM, BK=64, XOR-swizzled LDS (conflict-free) ----------------
// Proven 347us-baseline configs: in-proj <128,128,64,64>, out-proj <128,64,64,32>.
// (8-phase 256^2 experiments r1-r3 both measured SLOWER on this K=768 shape:
//  16 barriers/K-tile-pair at 1 block/CU lockstep; reverted.)
template<int BM, int BN, int WM, int WN, bool OUT_BF16>
__global__ __launch_bounds__(256)
void k_gemm_t(const unsigned short* __restrict__ A, const unsigned short* __restrict__ Bt,
              void* __restrict__ C0v, int ld0, int ncol0,
              void* __restrict__ C1v, int ld1, int K)
{
  constexpr int MI = WM / 16, NI = WN / 16;
  constexpr int WAVES_N = BN / WN;
  constexpr int RA = BM / 32, RB = BN / 32;
  const int m0 = blockIdx.x * BM, n0 = blockIdx.y * BN;
  __shared__ unsigned short As[BM][64];
  __shared__ unsigned short Bs[BN][64];
  const int tid  = threadIdx.x;
  const int wave = tid >> 6, lane = tid & 63;
  const int quad = lane >> 4, r16 = lane & 15;
  const int wm = (wave / WAVES_N) * WM, wn = (wave % WAVES_N) * WN;

  const int lr8 = lane >> 3;                                // 0..7 row-in-band
  const int csw = ((lane & 7) ^ lr8) * 8;                   // swizzled source col (shorts)
  const unsigned short* gA = A  + (size_t)(m0 + wave * 8 + lr8) * K + csw;
  const unsigned short* gB = Bt + (size_t)(n0 + wave * 8 + lr8) * K + csw;
  unsigned short* lA = &As[wave * 8][0] + (size_t)lane * 8; // +lane*16B
  unsigned short* lB = &Bs[wave * 8][0] + (size_t)lane * 8;

  f32x4 acc[MI][NI];
#pragma unroll
  for (int mi = 0; mi < MI; ++mi)
#pragma unroll
    for (int ni = 0; ni < NI; ++ni) acc[mi][ni] = (f32x4){0.f, 0.f, 0.f, 0.f};

  for (int k0 = 0; k0 < K; k0 += 64) {
#pragma unroll
    for (int r = 0; r < RA; ++r)
      gload16(gA + (size_t)(r * 32) * K + k0, lA + (size_t)r * 32 * 64);
#pragma unroll
    for (int r = 0; r < RB; ++r)
      gload16(gB + (size_t)(r * 32) * K + k0, lB + (size_t)r * 32 * 64);
    __syncthreads();
    bf16x8 af[MI][2], bfr[NI][2];
#pragma unroll
    for (int mi = 0; mi < MI; ++mi)
#pragma unroll
      for (int ks = 0; ks < 2; ++ks)
        af[mi][ks] = *(const bf16x8*)&As[wm + mi * 16 + r16][((quad + ks * 4) ^ (r16 & 7)) * 8];
#pragma unroll
    for (int ni = 0; ni < NI; ++ni)
#pragma unroll
      for (int ks = 0; ks < 2; ++ks)
        bfr[ni][ks] = *(const bf16x8*)&Bs[wn + ni * 16 + r16][((quad + ks * 4) ^ (r16 & 7)) * 8];
#pragma unroll
    for (int mi = 0; mi < MI; ++mi)
#pragma unroll
      for (int ni = 0; ni < NI; ++ni)
#pragma unroll
        for (int ks = 0; ks < 2; ++ks)
          acc[mi][ni] = __builtin_amdgcn_mfma_f32_16x16x32_bf16(
              af[mi][ks], bfr[ni][ks], acc[mi][ni], 0, 0, 0);
    __syncthreads();
  }
#pragma unroll
  for (int mi = 0; mi < MI; ++mi)
#pragma unroll
    for (int ni = 0; ni < NI; ++ni) {
      int col = n0 + wn + ni * 16 + r16;
      void* dst; int ld, c;
      if (col < ncol0) { dst = C0v; ld = ld0; c = col; }
      else             { dst = C1v; ld = ld1; c = col - ncol0; }
#pragma unroll
      for (int r = 0; r < 4; ++r) {
        int row = m0 + wm + mi * 16 + quad * 4 + r;
        if (OUT_BF16) ((unsigned short*)dst)[(size_t)row * ld + c] = f2bf(acc[mi][ni][r]);
        else          ((float*)dst)[(size_t)row * ld + c] = acc[mi][ni][r];
      }
    }
}

// ---------------- depthwise conv(4) + silu: sliding window, batch-boundary aware ----------------
__global__ __launch_bounds__(256)
void k_conv2(const unsigned short* __restrict__ xbc, const float* __restrict__ cw,
             const float* __restrict__ cb, _Float16* __restrict__ xs,
             float* __restrict__ Bm, float* __restrict__ Cm)
{
  const int ch = blockIdx.x * 256 + threadIdx.x;
  if (ch >= CD) return;
  const int r0 = blockIdx.y * CROWS;
  const float w0 = cw[ch * 4], w1 = cw[ch * 4 + 1], w2 = cw[ch * 4 + 2], w3 = cw[ch * 4 + 3];
  const float bias = cb[ch];
  float a, b, c;
  if ((r0 & (L_ - 1)) == 0) {                 // batch start: zero history
    a = 0.f; b = 0.f; c = 0.f;
  } else {
    a = bf2f(xbc[(size_t)(r0 - 3) * CD + ch]);
    b = bf2f(xbc[(size_t)(r0 - 2) * CD + ch]);
    c = bf2f(xbc[(size_t)(r0 - 1) * CD + ch]);
  }
#pragma unroll
  for (int i = 0; i < CROWS; ++i) {
    const int lr = r0 + i;
    float d = bf2f(xbc[(size_t)lr * CD + ch]);
    float v = siluf(bias + a * w0 + b * w1 + c * w2 + d * w3);
    a = b; b = c; c = d;
    if (ch < DI)           xs[(size_t)lr * DI + ch] = (_Float16)v;
    else if (ch < DI + DS) Bm[(size_t)lr * DS + (ch - DI)] = v;
    else                   Cm[(size_t)lr * DS + (ch - DI - DS)] = v;
  }
}

// ---------------- exact fp32 dt via LDS-staged WdtT + fused x->bf16 cast ----------------
// block = 192 threads = 24 heads x 8 rows; thread h also casts x chunk [h*32,h*32+32)
__global__ __launch_bounds__(192)
void k_dt2(const float* __restrict__ x, const float* __restrict__ WdtT,
           const float* __restrict__ dt_bias, float* __restrict__ dtv,
           unsigned short* __restrict__ xb)
{
  __shared__ float sW[H_][WDS];
  for (int i = threadIdx.x; i < H_ * DM; i += 192)
    sW[i / DM][i % DM] = WdtT[i];
  const int h = threadIdx.x % H_, rloc = threadIdx.x / H_;
  const int lrow = blockIdx.x * 8 + rloc;
  const float* xr = x + (size_t)lrow * DM;
  __syncthreads();
  float acc = 0.f;
#pragma unroll 8
  for (int k = 0; k < DM; k += 4) {
    f32x4 xv = *(const f32x4*)(xr + k);
    f32x4 wv = *(const f32x4*)&sW[h][k];
    acc += xv[0] * wv[0] + xv[1] * wv[1] + xv[2] * wv[2] + xv[3] * wv[3];
  }
  dtv[(size_t)lrow * H_ + h] = softplusf(acc + dt_bias[h]);
  // fused cast: 32-elem chunk per thread (L1-hot re-read)
  const float* xi = xr + h * 32;
  unsigned short* xo = xb + (size_t)lrow * DM + h * 32;
#pragma unroll
  for (int j = 0; j < 32; j += 8) {
    f32x4 a = *(const f32x4*)(xi + j);
    f32x4 b = *(const f32x4*)(xi + j + 4);
    us8 o;
#pragma unroll
    for (int e = 0; e < 4; ++e) { o[e] = f2bf(a[e]); o[e + 4] = f2bf(b[e]); }
    *(us8*)(xo + j) = o;
  }
}

// ---------------- per-chunk inclusive cumsum of dt*A ----------------
__global__ void k_cum(const float* __restrict__ dtv, const float* __restrict__ A_log,
                      float* __restrict__ cumA, int n)
{
  const int idx = blockIdx.x * 256 + threadIdx.x;      // ((bz*H+h)*NC + c)
  if (idx >= n) return;
  const int c = idx % NC;
  const int h = (idx / NC) % H_;
  const int bz = idx / (NC * H_);
  const float A = -expf(A_log[h]);
  float cum = 0.f;
  const int rowbase = bz * L_ + c * Q_;
  float* outp = cumA + (size_t)idx * Q_;
  for (int i = 0; i < Q_; ++i) {
    cum += dtv[(size_t)(rowbase + i) * H_ + h] * A;
    outp[i] = cum;
  }
}

// ---------------- intra-chunk via fp16 MFMA; ytot/Sbuf stored fp16 ----------------
// D*x is fused into the y-store here (X is already staged in sXT); k_inter no
// longer reads xs at all (-25 MB HBM stream).
__global__ __launch_bounds__(256)
void k_intra(const _Float16* __restrict__ xs, const float* __restrict__ Bm,
             const float* __restrict__ Cm, const float* __restrict__ dtv,
             const float* __restrict__ cumA, const float* __restrict__ Dp,
             _Float16* __restrict__ ytot, _Float16* __restrict__ Sbuf)
{
  const int c = blockIdx.x, h = blockIdx.y, bz = blockIdx.z;
  const int gidx = (bz * H_ + h) * NC + c;
  __shared__ _Float16 sCW[Q_][HS];   // C, then W
  __shared__ _Float16 sB [Q_][HS];
  __shared__ _Float16 sBT[Q_][HS];   // (coef_j * B[j][n]) transposed -> [n][j]
  __shared__ _Float16 sXT[Q_][HS];   // X transposed -> [p][j]
  __shared__ float scum[Q_], sdt[Q_];
  const int tid = threadIdx.x;
  const int rowbase = bz * L_ + c * Q_;

  {
    const int j = tid >> 2, s16 = (tid & 3) * 16;
    if (tid < Q_) {
      scum[tid] = cumA[(size_t)gidx * Q_ + tid];
      sdt[tid]  = dtv[(size_t)(rowbase + tid) * H_ + h];
    }
    const _Float16* xsrc = xs + (size_t)(rowbase + j) * DI + h * P_ + s16;
    f16x8 xv0 = *(const f16x8*)xsrc;
    f16x8 xv1 = *(const f16x8*)(xsrc + 8);
    f32x4 bv[4], cv[4];
    const float* bsrc = Bm + (size_t)(rowbase + j) * DS + s16;
    const float* csrc = Cm + (size_t)(rowbase + j) * DS + s16;
#pragma unroll
    for (int q = 0; q < 4; ++q) {
      bv[q] = *(const f32x4*)(bsrc + q * 4);
      cv[q] = *(const f32x4*)(csrc + q * 4);
    }
    __syncthreads();
    const float coef = expf(scum[Q_ - 1] - scum[j]) * sdt[j];
    union { f16x8 v; _Float16 e[8]; } pc[2], pb[2];
#pragma unroll
    for (int q = 0; q < 4; ++q)
#pragma unroll
      for (int e = 0; e < 4; ++e) {
        int o = q * 4 + e;
        pc[o >> 3].e[o & 7] = (_Float16)cv[q][e];
        pb[o >> 3].e[o & 7] = (_Float16)bv[q][e];
        sBT[s16 + o][j] = (_Float16)(bv[q][e] * coef);
        sXT[s16 + o][j] = (o < 8) ? xv0[o] : xv1[o - 8];
      }
    *(f16x8*)&sCW[j][s16]     = pc[0].v;
    *(f16x8*)&sCW[j][s16 + 8] = pc[1].v;
    *(f16x8*)&sB [j][s16]     = pb[0].v;
    *(f16x8*)&sB [j][s16 + 8] = pb[1].v;
  }
  __syncthreads();

  const int wave = tid >> 6, lane = tid & 63;
  const int quad = lane >> 4, r16 = lane & 15;
  const int i0 = wave * 16;
  const int irow = i0 + quad * 4;

  f32x4 g[4];
#pragma unroll
  for (int q = 0; q < 4; ++q) g[q] = (f32x4){0.f, 0.f, 0.f, 0.f};
#pragma unroll
  for (int ni = 0; ni < 4; ++ni) {
    if (ni <= wave) {
#pragma unroll
      for (int ks = 0; ks < 2; ++ks)
        g[ni] = __builtin_amdgcn_mfma_f32_16x16x32_f16(
            *(const f16x8*)&sCW[i0 + r16][ks * 32 + quad * 8],
            *(const f16x8*)&sB [ni * 16 + r16][ks * 32 + quad * 8], g[ni], 0, 0, 0);
    }
  }
  float wv[4][4];
#pragma unroll
  for (int ni = 0; ni < 4; ++ni)
#pragma unroll
    for (int r = 0; r < 4; ++r) {
      int i = irow + r, jcol = ni * 16 + r16;
      float v = 0.f;
      if (ni <= wave && jcol <= i)
        v = g[ni][r] * expf(scum[i] - scum[jcol]) * sdt[jcol];
      wv[ni][r] = v;
    }
  __syncthreads();
#pragma unroll
  for (int ni = 0; ni < 4; ++ni)
#pragma unroll
    for (int r = 0; r < 4; ++r)
      sCW[irow + r][ni * 16 + r16] = (_Float16)wv[ni][r];
  __syncthreads();

  const float Dh = Dp[h];
  f32x4 y[4];
#pragma unroll
  for (int q = 0; q < 4; ++q) y[q] = (f32x4){0.f, 0.f, 0.f, 0.f};
#pragma unroll
  for (int ni = 0; ni < 4; ++ni)
#pragma unroll
    for (int ks = 0; ks < 2; ++ks) {
      if (ks == 0 || wave >= 2)
        y[ni] = __builtin_amdgcn_mfma_f32_16x16x32_f16(
            *(const f16x8*)&sCW[i0 + r16][ks * 32 + quad * 8],
            *(const f16x8*)&sXT[ni * 16 + r16][ks * 32 + quad * 8], y[ni], 0, 0, 0);
    }
#pragma unroll
  for (int ni = 0; ni < 4; ++ni)
#pragma unroll
    for (int r = 0; r < 4; ++r) {
      const float xval = (float)sXT[ni * 16 + r16][irow + r];   // X[irow+r][ni*16+r16]
      ytot[(size_t)(rowbase + irow + r) * DI + h * P_ + ni * 16 + r16] =
          (_Float16)(y[ni][r] + Dh * xval);
    }

  f32x4 t4[4];
#pragma unroll
  for (int q = 0; q < 4; ++q) t4[q] = (f32x4){0.f, 0.f, 0.f, 0.f};
#pragma unroll
  for (int ni = 0; ni < 4; ++ni)
#pragma unroll
    for (int ks = 0; ks < 2; ++ks)
      t4[ni] = __builtin_amdgcn_mfma_f32_16x16x32_f16(
          *(const f16x8*)&sBT[i0 + r16][ks * 32 + quad * 8],
          *(const f16x8*)&sXT[ni * 16 + r16][ks * 32 + quad * 8], t4[ni], 0, 0, 0);
  _Float16* sp = Sbuf + (size_t)gidx * (DS * P_);
#pragma unroll
  for (int ni = 0; ni < 4; ++ni)
#pragma unroll
    for (int r = 0; r < 4; ++r)
      sp[(irow + r) * P_ + ni * 16 + r16] = (_Float16)t4[ni][r];
}

// ---------------- sequential inter-chunk recurrence (in-place, fp16 storage) ----------------
// Manual prefetch of chunk c+1 before the chunk-c store: the in-place RMW on the
// same pointer otherwise blocks the compiler from hoisting the next load past the
// store (alias), serializing 64 full-latency memory round-trips per thread.
__global__ void k_chunkscan(_Float16* __restrict__ Sbuf, const float* __restrict__ cumA)
{
  const int seg = blockIdx.x, h = blockIdx.y, bz = blockIdx.z;
  const int bh = bz * H_ + h;
  __shared__ float dec[NC];
  const int tid = threadIdx.x;
  if (tid < NC) dec[tid] = expf(cumA[((size_t)(bh * NC + tid)) * Q_ + (Q_ - 1)]);
  __syncthreads();
  const size_t off = (size_t)seg * 512 + (size_t)tid * 8;
  float s[8];
#pragma unroll
  for (int e = 0; e < 8; ++e) s[e] = 0.f;
  _Float16* p = Sbuf + (size_t)bh * NC * (DS * P_) + off;
  f16x8 v = *(const f16x8*)p;                    // chunk 0
  for (int c = 0; c < NC; ++c) {
    _Float16* pn = p + (size_t)(DS * P_);
    f16x8 vn = v;
    if (c + 1 < NC) vn = *(const f16x8*)pn;      // prefetch chunk c+1 (independent)
    f16x8 sto;
#pragma unroll
    for (int e = 0; e < 8; ++e) sto[e] = (_Float16)s[e];
    *(f16x8*)p = sto;                            // store state BEFORE chunk c
    const float d = dec[c];
#pragma unroll
    for (int e = 0; e < 8; ++e) s[e] = s[e] * d + (float)v[e];
    v = vn; p = pn;
  }
}

// ---------------- inter-chunk correction (ytot fp16 RMW); D*x moved to k_intra ----------------
__global__ __launch_bounds__(256)
void k_inter(const float* __restrict__ Cm, const float* __restrict__ cumA,
             const _Float16* __restrict__ Sbuf, _Float16* __restrict__ ytot)
{
  const int c = blockIdx.x, h = blockIdx.y, bz = blockIdx.z;
  const int gidx = (bz * H_ + h) * NC + c;
  __shared__ float sS[DS][SP];
  __shared__ float sC[Q_][SP];
  __shared__ float scum[Q_];
  const int tid = threadIdx.x;
  const int jr = tid >> 2, blk = (tid & 3) * 16;
  const int rowbase = bz * L_ + c * Q_;
  {
    const _Float16* ssrc = Sbuf + (size_t)gidx * (DS * P_) + jr * P_ + blk;
    f16x8 sv0 = *(const f16x8*)ssrc;
    f16x8 sv1 = *(const f16x8*)(ssrc + 8);
    const float* csrc = Cm + (size_t)(rowbase + jr) * DS + blk;
#pragma unroll
    for (int o = 0; o < 8; ++o) {
      sS[jr][blk + o]     = (float)sv0[o];
      sS[jr][blk + 8 + o] = (float)sv1[o];
    }
#pragma unroll
    for (int q = 0; q < 4; ++q)
      *(f32x4*)&sC[jr][blk + q * 4] = *(const f32x4*)(csrc + q * 4);
    if (tid < Q_) scum[tid] = cumA[(size_t)gidx * Q_ + tid];
  }
  __syncthreads();
  const int i = jr;
  f32x4 acc[4];
#pragma unroll
  for (int q = 0; q < 4; ++q) acc[q] = (f32x4){0.f, 0.f, 0.f, 0.f};
  for (int n = 0; n < DS; ++n) {
    float cv = sC[i][n];
#pragma unroll
    for (int q = 0; q < 4; ++q) acc[q] += cv * *(const f32x4*)&sS[n][blk + q * 4];
  }
  const float e = expf(scum[i]);
  _Float16* yt = ytot + (size_t)(rowbase + i) * DI + h * P_ + blk;
  f16x8 y0 = *(const f16x8*)yt;
  f16x8 y1 = *(const f16x8*)(yt + 8);
#pragma unroll
  for (int o = 0; o < 16; ++o) {
    float cur = (float)((o < 8) ? y0[o] : y1[o - 8]);
    cur += e * acc[o >> 2][o & 3];
    if (o < 8) y0[o] = (_Float16)cur; else y1[o - 8] = (_Float16)cur;
  }
  *(f16x8*)yt = y0;
  *(f16x8*)(yt + 8) = y1;
}

// ---------------- gate (silu(z)) + RMSNorm + cast bf16 ----------------
__global__ __launch_bounds__(192)
void k_rms(const unsigned short* __restrict__ z, const _Float16* __restrict__ ytot,
           const float* __restrict__ norm_w, unsigned short* __restrict__ ynorm)
{
  const int row = blockIdx.x, tid = threadIdx.x;
  const int e0 = tid * 8;
  us8 zv = *(const us8*)(z + (size_t)row * DI + e0);
  f16x8 yv = *(const f16x8*)(ytot + (size_t)row * DI + e0);
  float g[8];
  float ss = 0.f;
#pragma unroll
  for (int q = 0; q < 8; ++q) {
    g[q] = (float)yv[q] * siluf(bf2f(zv[q]));
    ss += g[q] * g[q];
  }
#pragma unroll
  for (int off = 32; off > 0; off >>= 1) ss += __shfl_down(ss, off);
  __shared__ float wsum[3];
  __shared__ float sscale;
  if ((tid & 63) == 0) wsum[tid >> 6] = ss;
  __syncthreads();
  if (tid == 0) sscale = rsqrtf((wsum[0] + wsum[1] + wsum[2]) * (1.f / DI) + 1e-5f);
  __syncthreads();
  const float sc = sscale;
  us8 o;
#pragma unroll
  for (int q = 0; q < 8; ++q) o[q] = f2bf(g[q] * sc * norm_w[e0 + q]);
  *(us8*)(ynorm + (size_t)row * DI + e0) = o;
}

extern "C" void kernel_launch(void* const* d_in, const int* in_sizes, int n_in,
                              void* d_out, int out_size, void* d_ws, size_t ws_size,
                              hipStream_t stream)
{
  (void)in_sizes; (void)n_in; (void)out_size;
  const float* x       = (const float*)d_in[0];
  const float* W_in    = (const float*)d_in[1];
  const float* conv_w  = (const float*)d_in[2];
  const float* conv_b  = (const float*)d_in[3];
  const float* dt_bias = (const float*)d_in[4];
  const float* A_log   = (const float*)d_in[5];
  const float* Dp      = (const float*)d_in[6];
  const float* norm_w  = (const float*)d_in[7];
  const float* W_out   = (const float*)d_in[8];
  float* out = (float*)d_out;

  // ---- batches per pass: footprint(nb) = nb*L_*16320 + 7,385,088 ----
  const int nb = ((size_t)2 * L_ * 16320 + 7385088 <= ws_size) ? 2 : 1;
  const int rows = nb * L_;

  // ---- workspace layout (per-pass buffers) ----
  char* ws = (char*)d_ws;
  unsigned short* zseg = (unsigned short*)ws;  ws += (size_t)rows * DI * 2;   // bf16 z
  unsigned short* xbc  = (unsigned short*)ws;  ws += (size_t)rows * CD * 2;   // bf16 xBC
  _Float16* xs   = (_Float16*)ws;  ws += (size_t)rows * DI * 2;               // fp16 conv-x
  _Float16* ytot = (_Float16*)ws;  ws += (size_t)rows * DI * 2;               // fp16 y
  float* Bm   = (float*)ws;  ws += (size_t)rows * DS * 4;
  float* Cm   = (float*)ws;  ws += (size_t)rows * DS * 4;
  float* dtv  = (float*)ws;  ws += (size_t)rows * H_ * 4;
  float* cumA = (float*)ws;  ws += (size_t)rows * H_ * 4;
  _Float16* Sbuf = (_Float16*)ws;  ws += (size_t)rows * 3072;  // nb*H_*NC*DS*P_*2
  unsigned short* WinT  = (unsigned short*)ws; ws += (size_t)NPJ * DM * 2;
  unsigned short* WoutT = (unsigned short*)ws; ws += (size_t)DM * DI * 2;
  float* WdtT   = (float*)ws;  ws += (size_t)H_ * DM * 4;
  unsigned short* xb    = (unsigned short*)Sbuf;     // overlay: Sbuf dead until k_intra
  unsigned short* ynorm = (unsigned short*)xs;       // overlay: xs dead after k_inter

  k_transpose_cast<<<dim3(24, (NPJ + 31) / 32), 256, 0, stream>>>(W_in, WinT, DM, NPJ);
  k_transpose_cast<<<dim3(48, 24), 256, 0, stream>>>(W_out, WoutT, DI, DM);
  k_wdtT<<<(H_ * DM + 255) / 256, 256, 0, stream>>>(W_in, WdtT);

  for (int b0 = 0; b0 < B_; b0 += nb) {
    const float* xp = x + (size_t)b0 * L_ * DM;

    k_dt2<<<rows / 8, 192, 0, stream>>>(xp, WdtT, dt_bias, dtv, xb);
    k_gemm_t<128, 128, 64, 64, true><<<dim3(rows / 128, N1 / 128), 256, 0, stream>>>(
        xb, WinT, zseg, DI, DI, xbc, CD, DM);
    k_conv2<<<dim3(7, rows / CROWS), 256, 0, stream>>>(xbc, conv_w, conv_b, xs, Bm, Cm);
    k_cum<<<(nb * H_ * NC + 255) / 256, 256, 0, stream>>>(dtv, A_log, cumA, nb * H_ * NC);
    k_intra<<<dim3(NC, H_, nb), 256, 0, stream>>>(xs, Bm, Cm, dtv, cumA, Dp, ytot, Sbuf);
    k_chunkscan<<<dim3(8, H_, nb), 64, 0, stream>>>(Sbuf, cumA);
    k_inter<<<dim3(NC, H_, nb), 256, 0, stream>>>(Cm, cumA, Sbuf, ytot);
    k_rms<<<rows, 192, 0, stream>>>(zseg, ytot, norm_w, ynorm);
    k_gemm_t<128, 64, 64, 32, false><<<dim3(rows / 128, DM / 64), 256, 0, stream>>>(
        ynorm, WoutT, out + (size_t)b0 * L_ * DM, DM, DM, out + (size_t)b0 * L_ * DM, DM, DI);
  }
}

// Round 5
// 321.267 us; speedup vs baseline: 1.2243x; 1.0905x over previous
//
#include <hip/hip_runtime.h>

// ---- problem constants ----
#define B_   2
#define L_   4096
#define DM   768
#define DI   1536     // D_INNER
#define DS   64       // D_STATE
#define H_   24       // NHEADS
#define P_   64       // HEADDIM
#define CD   1664     // CONV_DIM
#define NPJ  3224     // D_IN_PROJ
#define N1   3200     // GEMM1 useful cols (z + xBC; dt cols done exactly in k_dt2)
#define Q_   64       // chunk length
#define NC   64       // chunks per batch
#define SP   76       // LDS row stride (floats) for k_inter tiles
#define HS   72       // fp16 LDS row stride (halves): <=2-way conflicts
#define WDS  772      // k_dt2 LDS W stride
#define CROWS 16      // conv rows per thread

typedef short          bf16x8 __attribute__((ext_vector_type(8)));
typedef _Float16       f16x8  __attribute__((ext_vector_type(8)));
typedef _Float16       f16x4  __attribute__((ext_vector_type(4)));
typedef unsigned short us8    __attribute__((ext_vector_type(8)));
typedef unsigned short us4    __attribute__((ext_vector_type(4)));
typedef float          f32x4  __attribute__((ext_vector_type(4)));

__device__ __forceinline__ unsigned short f2bf(float f) {
  unsigned u = __float_as_uint(f);
  u += 0x7fffu + ((u >> 16) & 1u);   // RNE
  return (unsigned short)(u >> 16);
}
__device__ __forceinline__ float bf2f(unsigned short u) {
  return __uint_as_float(((unsigned)u) << 16);
}
__device__ __forceinline__ float siluf(float x) { return x / (1.f + expf(-x)); }
__device__ __forceinline__ float softplusf(float x) { return (x > 20.f) ? x : log1pf(expf(x)); }

// async global->LDS, 16B per lane; LDS dest = uniform base + lane*16
__device__ __forceinline__ void gload16(const unsigned short* g, unsigned short* l) {
  __builtin_amdgcn_global_load_lds(
      (const __attribute__((address_space(1))) void*)g,
      (__attribute__((address_space(3))) void*)l, 16, 0, 0);
}

// ---------------- transpose + cast (R x C fp32) -> (C x R bf16) ----------------
__global__ __launch_bounds__(256)
void k_transpose_cast(const float* __restrict__ src, unsigned short* __restrict__ dst,
                      int R, int C)
{
  __shared__ float tile[32][33];
  const int tx = threadIdx.x & 31, ty = threadIdx.x >> 5;
  const int r0 = blockIdx.x * 32, c0 = blockIdx.y * 32;
#pragma unroll
  for (int r = 0; r < 4; ++r) {
    int rr = r0 + ty + r * 8, cc = c0 + tx;
    if (rr < R && cc < C) tile[ty + r * 8][tx] = src[(size_t)rr * C + cc];
  }
  __syncthreads();
#pragma unroll
  for (int r = 0; r < 4; ++r) {
    int orow = c0 + ty + r * 8, ocol = r0 + tx;
    if (orow < C && ocol < R) dst[(size_t)orow * R + ocol] = f2bf(tile[tx][ty + r * 8]);
  }
}

// ---------------- gather dt columns of W_in -> contiguous fp32 WdtT[24][768] ----------------
__global__ void k_wdtT(const float* __restrict__ W_in, float* __restrict__ WdtT)
{
  const int idx = blockIdx.x * 256 + threadIdx.x;
  if (idx >= H_ * DM) return;
  const int k = idx / H_, h = idx % H_;
  WdtT[(size_t)h * DM + k] = W_in[(size_t)k * NPJ + N1 + h];
}

// ---------------- bf16 MFMA GEMM, BK=64, XOR-swizzled LDS (conflict-free) ----------------
// Proven 347us-baseline configs: in-proj <128,128,64,64>, out-proj <128,64,64,32>.
// (8-phase 256^2 experiments r1-r3 measured SLOWER on this K=768 shape; reverted.)
template<int BM, int BN, int WM, int WN, bool OUT_BF16>
__global__ __launch_bounds__(256)
void k_gemm_t(const unsigned short* __restrict__ A, const unsigned short* __restrict__ Bt,
              void* __restrict__ C0v, int ld0, int ncol0,
              void* __restrict__ C1v, int ld1, int K)
{
  constexpr int MI = WM / 16, NI = WN / 16;
  constexpr int WAVES_N = BN / WN;
  constexpr int RA = BM / 32, RB = BN / 32;
  const int m0 = blockIdx.x * BM, n0 = blockIdx.y * BN;
  __shared__ unsigned short As[BM][64];
  __shared__ unsigned short Bs[BN][64];
  const int tid  = threadIdx.x;
  const int wave = tid >> 6, lane = tid & 63;
  const int quad = lane >> 4, r16 = lane & 15;
  const int wm = (wave / WAVES_N) * WM, wn = (wave % WAVES_N) * WN;

  const int lr8 = lane >> 3;                                // 0..7 row-in-band
  const int csw = ((lane & 7) ^ lr8) * 8;                   // swizzled source col (shorts)
  const unsigned short* gA = A  + (size_t)(m0 + wave * 8 + lr8) * K + csw;
  const unsigned short* gB = Bt + (size_t)(n0 + wave * 8 + lr8) * K + csw;
  unsigned short* lA = &As[wave * 8][0] + (size_t)lane * 8; // +lane*16B
  unsigned short* lB = &Bs[wave * 8][0] + (size_t)lane * 8;

  f32x4 acc[MI][NI];
#pragma unroll
  for (int mi = 0; mi < MI; ++mi)
#pragma unroll
    for (int ni = 0; ni < NI; ++ni) acc[mi][ni] = (f32x4){0.f, 0.f, 0.f, 0.f};

  for (int k0 = 0; k0 < K; k0 += 64) {
#pragma unroll
    for (int r = 0; r < RA; ++r)
      gload16(gA + (size_t)(r * 32) * K + k0, lA + (size_t)r * 32 * 64);
#pragma unroll
    for (int r = 0; r < RB; ++r)
      gload16(gB + (size_t)(r * 32) * K + k0, lB + (size_t)r * 32 * 64);
    __syncthreads();
    bf16x8 af[MI][2], bfr[NI][2];
#pragma unroll
    for (int mi = 0; mi < MI; ++mi)
#pragma unroll
      for (int ks = 0; ks < 2; ++ks)
        af[mi][ks] = *(const bf16x8*)&As[wm + mi * 16 + r16][((quad + ks * 4) ^ (r16 & 7)) * 8];
#pragma unroll
    for (int ni = 0; ni < NI; ++ni)
#pragma unroll
      for (int ks = 0; ks < 2; ++ks)
        bfr[ni][ks] = *(const bf16x8*)&Bs[wn + ni * 16 + r16][((quad + ks * 4) ^ (r16 & 7)) * 8];
#pragma unroll
    for (int mi = 0; mi < MI; ++mi)
#pragma unroll
      for (int ni = 0; ni < NI; ++ni)
#pragma unroll
        for (int ks = 0; ks < 2; ++ks)
          acc[mi][ni] = __builtin_amdgcn_mfma_f32_16x16x32_bf16(
              af[mi][ks], bfr[ni][ks], acc[mi][ni], 0, 0, 0);
    __syncthreads();
  }
#pragma unroll
  for (int mi = 0; mi < MI; ++mi)
#pragma unroll
    for (int ni = 0; ni < NI; ++ni) {
      int col = n0 + wn + ni * 16 + r16;
      void* dst; int ld, c;
      if (col < ncol0) { dst = C0v; ld = ld0; c = col; }
      else             { dst = C1v; ld = ld1; c = col - ncol0; }
#pragma unroll
      for (int r = 0; r < 4; ++r) {
        int row = m0 + wm + mi * 16 + quad * 4 + r;
        if (OUT_BF16) ((unsigned short*)dst)[(size_t)row * ld + c] = f2bf(acc[mi][ni][r]);
        else          ((float*)dst)[(size_t)row * ld + c] = acc[mi][ni][r];
      }
    }
}

// ---------------- depthwise conv(4) + silu: sliding window, batch-boundary aware ----------------
__global__ __launch_bounds__(256)
void k_conv2(const unsigned short* __restrict__ xbc, const float* __restrict__ cw,
             const float* __restrict__ cb, _Float16* __restrict__ xs,
             float* __restrict__ Bm, float* __restrict__ Cm)
{
  const int ch = blockIdx.x * 256 + threadIdx.x;
  if (ch >= CD) return;
  const int r0 = blockIdx.y * CROWS;
  const float w0 = cw[ch * 4], w1 = cw[ch * 4 + 1], w2 = cw[ch * 4 + 2], w3 = cw[ch * 4 + 3];
  const float bias = cb[ch];
  float a, b, c;
  if ((r0 & (L_ - 1)) == 0) {                 // batch start: zero history
    a = 0.f; b = 0.f; c = 0.f;
  } else {
    a = bf2f(xbc[(size_t)(r0 - 3) * CD + ch]);
    b = bf2f(xbc[(size_t)(r0 - 2) * CD + ch]);
    c = bf2f(xbc[(size_t)(r0 - 1) * CD + ch]);
  }
#pragma unroll
  for (int i = 0; i < CROWS; ++i) {
    const int lr = r0 + i;
    float d = bf2f(xbc[(size_t)lr * CD + ch]);
    float v = siluf(bias + a * w0 + b * w1 + c * w2 + d * w3);
    a = b; b = c; c = d;
    if (ch < DI)           xs[(size_t)lr * DI + ch] = (_Float16)v;
    else if (ch < DI + DS) Bm[(size_t)lr * DS + (ch - DI)] = v;
    else                   Cm[(size_t)lr * DS + (ch - DI - DS)] = v;
  }
}

// ---------------- exact fp32 dt via LDS-staged WdtT + fused x->bf16 cast ----------------
// block = 192 threads = 24 heads x 8 rows; thread h also casts x chunk [h*32,h*32+32)
__global__ __launch_bounds__(192)
void k_dt2(const float* __restrict__ x, const float* __restrict__ WdtT,
           const float* __restrict__ dt_bias, float* __restrict__ dtv,
           unsigned short* __restrict__ xb)
{
  __shared__ float sW[H_][WDS];
  for (int i = threadIdx.x; i < H_ * DM; i += 192)
    sW[i / DM][i % DM] = WdtT[i];
  const int h = threadIdx.x % H_, rloc = threadIdx.x / H_;
  const int lrow = blockIdx.x * 8 + rloc;
  const float* xr = x + (size_t)lrow * DM;
  __syncthreads();
  float acc = 0.f;
#pragma unroll 8
  for (int k = 0; k < DM; k += 4) {
    f32x4 xv = *(const f32x4*)(xr + k);
    f32x4 wv = *(const f32x4*)&sW[h][k];
    acc += xv[0] * wv[0] + xv[1] * wv[1] + xv[2] * wv[2] + xv[3] * wv[3];
  }
  dtv[(size_t)lrow * H_ + h] = softplusf(acc + dt_bias[h]);
  // fused cast: 32-elem chunk per thread (L1-hot re-read)
  const float* xi = xr + h * 32;
  unsigned short* xo = xb + (size_t)lrow * DM + h * 32;
#pragma unroll
  for (int j = 0; j < 32; j += 8) {
    f32x4 a = *(const f32x4*)(xi + j);
    f32x4 b = *(const f32x4*)(xi + j + 4);
    us8 o;
#pragma unroll
    for (int e = 0; e < 4; ++e) { o[e] = f2bf(a[e]); o[e + 4] = f2bf(b[e]); }
    *(us8*)(xo + j) = o;
  }
}

// ---------------- intra-chunk via fp16 MFMA; ytot/Sbuf stored fp16 ----------------
// Round-5: k_cum is FUSED here. Wave 0 computes scum via __shfl_up inclusive scan
// of sdt (x A = -exp(A_log[h])) and writes cumA out for k_chunkscan / k_inter.
// D*x fused into the y-store (X staged in sXT); k_inter does not read xs.
__global__ __launch_bounds__(256)
void k_intra(const _Float16* __restrict__ xs, const float* __restrict__ Bm,
             const float* __restrict__ Cm, const float* __restrict__ dtv,
             const float* __restrict__ A_log, const float* __restrict__ Dp,
             float* __restrict__ cumA, _Float16* __restrict__ ytot,
             _Float16* __restrict__ Sbuf)
{
  const int c = blockIdx.x, h = blockIdx.y, bz = blockIdx.z;
  const int gidx = (bz * H_ + h) * NC + c;
  __shared__ _Float16 sCW[Q_][HS];   // C, then W
  __shared__ _Float16 sB [Q_][HS];
  __shared__ _Float16 sBT[Q_][HS];   // (coef_j * B[j][n]) transposed -> [n][j]
  __shared__ _Float16 sXT[Q_][HS];   // X transposed -> [p][j]
  __shared__ float scum[Q_], sdt[Q_];
  const int tid = threadIdx.x;
  const int rowbase = bz * L_ + c * Q_;

  {
    const int j = tid >> 2, s16 = (tid & 3) * 16;
    if (tid < Q_) {                       // wave 0 only: scan dt -> scum, emit cumA
      const float dtval = dtv[(size_t)(rowbase + tid) * H_ + h];
      sdt[tid] = dtval;
      const float A = -expf(A_log[h]);
      float v = dtval;
#pragma unroll
      for (int off = 1; off < 64; off <<= 1) {
        float o = __shfl_up(v, off, 64);
        if (tid >= off) v += o;
      }
      v *= A;
      scum[tid] = v;
      cumA[(size_t)gidx * Q_ + tid] = v;
    }
    const _Float16* xsrc = xs + (size_t)(rowbase + j) * DI + h * P_ + s16;
    f16x8 xv0 = *(const f16x8*)xsrc;
    f16x8 xv1 = *(const f16x8*)(xsrc + 8);
    f32x4 bv[4], cv[4];
    const float* bsrc = Bm + (size_t)(rowbase + j) * DS + s16;
    const float* csrc = Cm + (size_t)(rowbase + j) * DS + s16;
#pragma unroll
    for (int q = 0; q < 4; ++q) {
      bv[q] = *(const f32x4*)(bsrc + q * 4);
      cv[q] = *(const f32x4*)(csrc + q * 4);
    }
    __syncthreads();
    const float coef = expf(scum[Q_ - 1] - scum[j]) * sdt[j];
    union { f16x8 v; _Float16 e[8]; } pc[2], pb[2];
#pragma unroll
    for (int q = 0; q < 4; ++q)
#pragma unroll
      for (int e = 0; e < 4; ++e) {
        int o = q * 4 + e;
        pc[o >> 3].e[o & 7] = (_Float16)cv[q][e];
        pb[o >> 3].e[o & 7] = (_Float16)bv[q][e];
        sBT[s16 + o][j] = (_Float16)(bv[q][e] * coef);
        sXT[s16 + o][j] = (o < 8) ? xv0[o] : xv1[o - 8];
      }
    *(f16x8*)&sCW[j][s16]     = pc[0].v;
    *(f16x8*)&sCW[j][s16 + 8] = pc[1].v;
    *(f16x8*)&sB [j][s16]     = pb[0].v;
    *(f16x8*)&sB [j][s16 + 8] = pb[1].v;
  }
  __syncthreads();

  const int wave = tid >> 6, lane = tid & 63;
  const int quad = lane >> 4, r16 = lane & 15;
  const int i0 = wave * 16;
  const int irow = i0 + quad * 4;

  f32x4 g[4];
#pragma unroll
  for (int q = 0; q < 4; ++q) g[q] = (f32x4){0.f, 0.f, 0.f, 0.f};
#pragma unroll
  for (int ni = 0; ni < 4; ++ni) {
    if (ni <= wave) {
#pragma unroll
      for (int ks = 0; ks < 2; ++ks)
        g[ni] = __builtin_amdgcn_mfma_f32_16x16x32_f16(
            *(const f16x8*)&sCW[i0 + r16][ks * 32 + quad * 8],
            *(const f16x8*)&sB [ni * 16 + r16][ks * 32 + quad * 8], g[ni], 0, 0, 0);
    }
  }
  float wv[4][4];
#pragma unroll
  for (int ni = 0; ni < 4; ++ni)
#pragma unroll
    for (int r = 0; r < 4; ++r) {
      int i = irow + r, jcol = ni * 16 + r16;
      float v = 0.f;
      if (ni <= wave && jcol <= i)
        v = g[ni][r] * expf(scum[i] - scum[jcol]) * sdt[jcol];
      wv[ni][r] = v;
    }
  __syncthreads();
#pragma unroll
  for (int ni = 0; ni < 4; ++ni)
#pragma unroll
    for (int r = 0; r < 4; ++r)
      sCW[irow + r][ni * 16 + r16] = (_Float16)wv[ni][r];
  __syncthreads();

  const float Dh = Dp[h];
  f32x4 y[4];
#pragma unroll
  for (int q = 0; q < 4; ++q) y[q] = (f32x4){0.f, 0.f, 0.f, 0.f};
#pragma unroll
  for (int ni = 0; ni < 4; ++ni)
#pragma unroll
    for (int ks = 0; ks < 2; ++ks) {
      if (ks == 0 || wave >= 2)
        y[ni] = __builtin_amdgcn_mfma_f32_16x16x32_f16(
            *(const f16x8*)&sCW[i0 + r16][ks * 32 + quad * 8],
            *(const f16x8*)&sXT[ni * 16 + r16][ks * 32 + quad * 8], y[ni], 0, 0, 0);
    }
#pragma unroll
  for (int ni = 0; ni < 4; ++ni)
#pragma unroll
    for (int r = 0; r < 4; ++r) {
      const float xval = (float)sXT[ni * 16 + r16][irow + r];   // X[irow+r][ni*16+r16]
      ytot[(size_t)(rowbase + irow + r) * DI + h * P_ + ni * 16 + r16] =
          (_Float16)(y[ni][r] + Dh * xval);
    }

  f32x4 t4[4];
#pragma unroll
  for (int q = 0; q < 4; ++q) t4[q] = (f32x4){0.f, 0.f, 0.f, 0.f};
#pragma unroll
  for (int ni = 0; ni < 4; ++ni)
#pragma unroll
    for (int ks = 0; ks < 2; ++ks)
      t4[ni] = __builtin_amdgcn_mfma_f32_16x16x32_f16(
          *(const f16x8*)&sBT[i0 + r16][ks * 32 + quad * 8],
          *(const f16x8*)&sXT[ni * 16 + r16][ks * 32 + quad * 8], t4[ni], 0, 0, 0);
  _Float16* sp = Sbuf + (size_t)gidx * (DS * P_);
#pragma unroll
  for (int ni = 0; ni < 4; ++ni)
#pragma unroll
    for (int r = 0; r < 4; ++r)
      sp[(irow + r) * P_ + ni * 16 + r16] = (_Float16)t4[ni][r];
}

// ---------------- sequential inter-chunk recurrence (in-place, fp16 storage) ----------------
// Round-5: 16 segments (2x waves, 768 total) + group-of-8 double-buffered prefetch:
// 8 loads in flight issued a full group (~8 iterations) ahead of consumption, which
// actually covers the ~200-400cy latency (r4's depth-1 prefetch covered ~30cy: neutral).
__global__ __launch_bounds__(64)
void k_chunkscan(_Float16* __restrict__ Sbuf, const float* __restrict__ cumA)
{
  const int seg = blockIdx.x, h = blockIdx.y, bz = blockIdx.z;
  const int bh = bz * H_ + h;
  __shared__ float dec[NC];
  const int tid = threadIdx.x;
  dec[tid] = expf(cumA[((size_t)(bh * NC + tid)) * Q_ + (Q_ - 1)]);
  __syncthreads();
  _Float16* base = Sbuf + (size_t)bh * NC * (DS * P_) + (size_t)seg * 256 + (size_t)tid * 4;
  float s[4] = {0.f, 0.f, 0.f, 0.f};
  f16x4 bA[8], bB[8];
#pragma unroll
  for (int j = 0; j < 8; ++j) bA[j] = *(const f16x4*)(base + (size_t)j * (DS * P_));
#pragma unroll
  for (int g = 0; g < 8; ++g) {
    if (g + 1 < 8) {                       // prefetch next group into the other buffer
#pragma unroll
      for (int j = 0; j < 8; ++j) {
        f16x4 v = *(const f16x4*)(base + (size_t)((g + 1) * 8 + j) * (DS * P_));
        if (g & 1) bA[j] = v; else bB[j] = v;   // compile-time after full unroll
      }
    }
#pragma unroll
    for (int j = 0; j < 8; ++j) {
      const int c = g * 8 + j;
      f16x4 cur = (g & 1) ? bB[j] : bA[j];
      f16x4 sto;
#pragma unroll
      for (int e = 0; e < 4; ++e) sto[e] = (_Float16)s[e];
      *(f16x4*)(base + (size_t)c * (DS * P_)) = sto;       // state BEFORE chunk c
      const float d = dec[c];
#pragma unroll
      for (int e = 0; e < 4; ++e) s[e] = s[e] * d + (float)cur[e];
    }
  }
}

// ---------------- inter-chunk correction (ytot fp16 RMW); D*x lives in k_intra ----------------
__global__ __launch_bounds__(256)
void k_inter(const float* __restrict__ Cm, const float* __restrict__ cumA,
             const _Float16* __restrict__ Sbuf, _Float16* __restrict__ ytot)
{
  const int c = blockIdx.x, h = blockIdx.y, bz = blockIdx.z;
  const int gidx = (bz * H_ + h) * NC + c;
  __shared__ float sS[DS][SP];
  __shared__ float sC[Q_][SP];
  __shared__ float scum[Q_];
  const int tid = threadIdx.x;
  const int jr = tid >> 2, blk = (tid & 3) * 16;
  const int rowbase = bz * L_ + c * Q_;
  {
    const _Float16* ssrc = Sbuf + (size_t)gidx * (DS * P_) + jr * P_ + blk;
    f16x8 sv0 = *(const f16x8*)ssrc;
    f16x8 sv1 = *(const f16x8*)(ssrc + 8);
    const float* csrc = Cm + (size_t)(rowbase + jr) * DS + blk;
#pragma unroll
    for (int o = 0; o < 8; ++o) {
      sS[jr][blk + o]     = (float)sv0[o];
      sS[jr][blk + 8 + o] = (float)sv1[o];
    }
#pragma unroll
    for (int q = 0; q < 4; ++q)
      *(f32x4*)&sC[jr][blk + q * 4] = *(const f32x4*)(csrc + q * 4);
    if (tid < Q_) scum[tid] = cumA[(size_t)gidx * Q_ + tid];
  }
  __syncthreads();
  const int i = jr;
  f32x4 acc[4];
#pragma unroll
  for (int q = 0; q < 4; ++q) acc[q] = (f32x4){0.f, 0.f, 0.f, 0.f};
  for (int n = 0; n < DS; ++n) {
    float cv = sC[i][n];
#pragma unroll
    for (int q = 0; q < 4; ++q) acc[q] += cv * *(const f32x4*)&sS[n][blk + q * 4];
  }
  const float e = expf(scum[i]);
  _Float16* yt = ytot + (size_t)(rowbase + i) * DI + h * P_ + blk;
  f16x8 y0 = *(const f16x8*)yt;
  f16x8 y1 = *(const f16x8*)(yt + 8);
#pragma unroll
  for (int o = 0; o < 16; ++o) {
    float cur = (float)((o < 8) ? y0[o] : y1[o - 8]);
    cur += e * acc[o >> 2][o & 3];
    if (o < 8) y0[o] = (_Float16)cur; else y1[o - 8] = (_Float16)cur;
  }
  *(f16x8*)yt = y0;
  *(f16x8*)(yt + 8) = y1;
}

// ---------------- gate (silu(z)) + RMSNorm + cast bf16 ----------------
__global__ __launch_bounds__(192)
void k_rms(const unsigned short* __restrict__ z, const _Float16* __restrict__ ytot,
           const float* __restrict__ norm_w, unsigned short* __restrict__ ynorm)
{
  const int row = blockIdx.x, tid = threadIdx.x;
  const int e0 = tid * 8;
  us8 zv = *(const us8*)(z + (size_t)row * DI + e0);
  f16x8 yv = *(const f16x8*)(ytot + (size_t)row * DI + e0);
  float g[8];
  float ss = 0.f;
#pragma unroll
  for (int q = 0; q < 8; ++q) {
    g[q] = (float)yv[q] * siluf(bf2f(zv[q]));
    ss += g[q] * g[q];
  }
#pragma unroll
  for (int off = 32; off > 0; off >>= 1) ss += __shfl_down(ss, off);
  __shared__ float wsum[3];
  __shared__ float sscale;
  if ((tid & 63) == 0) wsum[tid >> 6] = ss;
  __syncthreads();
  if (tid == 0) sscale = rsqrtf((wsum[0] + wsum[1] + wsum[2]) * (1.f / DI) + 1e-5f);
  __syncthreads();
  const float sc = sscale;
  us8 o;
#pragma unroll
  for (int q = 0; q < 8; ++q) o[q] = f2bf(g[q] * sc * norm_w[e0 + q]);
  *(us8*)(ynorm + (size_t)row * DI + e0) = o;
}

extern "C" void kernel_launch(void* const* d_in, const int* in_sizes, int n_in,
                              void* d_out, int out_size, void* d_ws, size_t ws_size,
                              hipStream_t stream)
{
  (void)in_sizes; (void)n_in; (void)out_size;
  const float* x       = (const float*)d_in[0];
  const float* W_in    = (const float*)d_in[1];
  const float* conv_w  = (const float*)d_in[2];
  const float* conv_b  = (const float*)d_in[3];
  const float* dt_bias = (const float*)d_in[4];
  const float* A_log   = (const float*)d_in[5];
  const float* Dp      = (const float*)d_in[6];
  const float* norm_w  = (const float*)d_in[7];
  const float* W_out   = (const float*)d_in[8];
  float* out = (float*)d_out;

  // ---- batches per pass: footprint(nb) = nb*L_*16320 + 7,385,088 ----
  const int nb = ((size_t)2 * L_ * 16320 + 7385088 <= ws_size) ? 2 : 1;
  const int rows = nb * L_;

  // ---- workspace layout (per-pass buffers) ----
  char* ws = (char*)d_ws;
  unsigned short* zseg = (unsigned short*)ws;  ws += (size_t)rows * DI * 2;   // bf16 z
  unsigned short* xbc  = (unsigned short*)ws;  ws += (size_t)rows * CD * 2;   // bf16 xBC
  _Float16* xs   = (_Float16*)ws;  ws += (size_t)rows * DI * 2;               // fp16 conv-x
  _Float16* ytot = (_Float16*)ws;  ws += (size_t)rows * DI * 2;               // fp16 y
  float* Bm   = (float*)ws;  ws += (size_t)rows * DS * 4;
  float* Cm   = (float*)ws;  ws += (size_t)rows * DS * 4;
  float* dtv  = (float*)ws;  ws += (size_t)rows * H_ * 4;
  float* cumA = (float*)ws;  ws += (size_t)rows * H_ * 4;
  _Float16* Sbuf = (_Float16*)ws;  ws += (size_t)rows * 3072;  // nb*H_*NC*DS*P_*2
  unsigned short* WinT  = (unsigned short*)ws; ws += (size_t)NPJ * DM * 2;
  unsigned short* WoutT = (unsigned short*)ws; ws += (size_t)DM * DI * 2;
  float* WdtT   = (float*)ws;  ws += (size_t)H_ * DM * 4;
  unsigned short* xb    = (unsigned short*)Sbuf;     // overlay: Sbuf dead until k_intra
  unsigned short* ynorm = (unsigned short*)xs;       // overlay: xs dead after k_inter

  k_transpose_cast<<<dim3(24, (NPJ + 31) / 32), 256, 0, stream>>>(W_in, WinT, DM, NPJ);
  k_transpose_cast<<<dim3(48, 24), 256, 0, stream>>>(W_out, WoutT, DI, DM);
  k_wdtT<<<(H_ * DM + 255) / 256, 256, 0, stream>>>(W_in, WdtT);

  for (int b0 = 0; b0 < B_; b0 += nb) {
    const float* xp = x + (size_t)b0 * L_ * DM;

    k_dt2<<<rows / 8, 192, 0, stream>>>(xp, WdtT, dt_bias, dtv, xb);
    k_gemm_t<128, 128, 64, 64, true><<<dim3(rows / 128, N1 / 128), 256, 0, stream>>>(
        xb, WinT, zseg, DI, DI, xbc, CD, DM);
    k_conv2<<<dim3(7, rows / CROWS), 256, 0, stream>>>(xbc, conv_w, conv_b, xs, Bm, Cm);
    k_intra<<<dim3(NC, H_, nb), 256, 0, stream>>>(xs, Bm, Cm, dtv, A_log, Dp, cumA, ytot, Sbuf);
    k_chunkscan<<<dim3(16, H_, nb), 64, 0, stream>>>(Sbuf, cumA);
    k_inter<<<dim3(NC, H_, nb), 256, 0, stream>>>(Cm, cumA, Sbuf, ytot);
    k_rms<<<rows, 192, 0, stream>>>(zseg, ytot, norm_w, ynorm);
    k_gemm_t<128, 64, 64, 32, false><<<dim3(rows / 128, DM / 64), 256, 0, stream>>>(
        ynorm, WoutT, out + (size_t)b0 * L_ * DM, DM, DM, out + (size_t)b0 * L_ * DM, DM, DI);
  }
}